// Round 6
// baseline (517.910 us; speedup 1.0000x reference)
//
#include <hip/hip_runtime.h>

typedef __attribute__((ext_vector_type(8))) short s16x8;
typedef __attribute__((ext_vector_type(8))) __bf16 bf16x8;
typedef __attribute__((ext_vector_type(4))) float f32x4;

__device__ inline float bf2f(ushort u){ return __uint_as_float(((unsigned)u)<<16); }
__device__ inline ushort f2bf(float f){
  unsigned u = __float_as_uint(f);
  unsigned r = (u + 0x7fffu + ((u>>16)&1u)) >> 16;
  return (ushort)r;
}

__device__ inline void gl_lds16(const ushort* g, ushort* l){
  __builtin_amdgcn_global_load_lds(
      (const __attribute__((address_space(1))) unsigned int*)g,
      (__attribute__((address_space(3))) unsigned int*)l,
      16, 0, 0);
}

// ---------------- CSR build ----------------
__global__ void k_count(const int* __restrict__ ei, int* __restrict__ counts,
                        int E, int ET){
  int e = blockIdx.x*256 + threadIdx.x;
  if (e >= ET) return;
  int dst = (e < E) ? ei[E + e] : (e - E);
  atomicAdd(&counts[dst], 1);
}

__global__ __launch_bounds__(1024) void k_scan(const int* __restrict__ cnt,
                                               int* __restrict__ indptr, int N){
  __shared__ int part[1024];
  int t = threadIdx.x;
  int per = (N + 1023) / 1024;
  int base = t * per;
  int s = 0;
  for (int i = 0; i < per; ++i){ int idx = base + i; if (idx < N) s += cnt[idx]; }
  part[t] = s; __syncthreads();
  for (int off = 1; off < 1024; off <<= 1){
    int v = (t >= off) ? part[t-off] : 0;
    __syncthreads();
    if (t >= off) part[t] += v;
    __syncthreads();
  }
  int run = (t == 0) ? 0 : part[t-1];
  for (int i = 0; i < per; ++i){
    int idx = base + i;
    if (idx < N){ indptr[idx] = run; run += cnt[idx]; }
  }
  if (t == 1023) indptr[N] = run;
}

__global__ void k_fill(const int* __restrict__ ei, const float* __restrict__ ew,
                       const int* __restrict__ indptr, int* __restrict__ cursor,
                       int* __restrict__ csrc, float* __restrict__ cew,
                       int E, int ET){
  int e = blockIdx.x*256 + threadIdx.x;
  if (e >= ET) return;
  int src, dst; float w;
  if (e < E){ src = ei[e]; dst = ei[E + e]; w = ew[e]; }
  else { src = dst = e - E; w = 1.0f; }
  int pos = indptr[dst] + atomicAdd(&cursor[dst], 1);
  csrc[pos] = src; cew[pos] = w;
}

// ---------------- conversions / packing ----------------
__global__ void k_f2b(const float* __restrict__ x, ushort* __restrict__ xb,
                      int n8valid, int n8total){
  int i = blockIdx.x*256 + threadIdx.x;
  if (i >= n8total) return;
  s16x8 o = {0,0,0,0,0,0,0,0};
  if (i < n8valid){
    const float4* p = (const float4*)x + (size_t)i*2;
    float4 a = p[0], b = p[1];
    o[0]=(short)f2bf(a.x); o[1]=(short)f2bf(a.y); o[2]=(short)f2bf(a.z); o[3]=(short)f2bf(a.w);
    o[4]=(short)f2bf(b.x); o[5]=(short)f2bf(b.y); o[6]=(short)f2bf(b.z); o[7]=(short)f2bf(b.w);
  }
  *((s16x8*)xb + i) = o;
}

__global__ __launch_bounds__(256) void k_packB(
    const float* __restrict__ W, const float* __restrict__ LW,
    ushort* __restrict__ BT, int K, int NW, int NL, int Npad)
{
  __shared__ float tile[32][33];
  int k0 = blockIdx.x*32, n0 = blockIdx.y*32;
  int c = threadIdx.x & 31, r4 = threadIdx.x >> 5;
  #pragma unroll
  for (int rr = 0; rr < 32; rr += 8){
    int k = k0 + r4 + rr, n = n0 + c;
    float v = 0.f;
    if (k < K){
      if (n < NW)            v = W[(size_t)k*NW + n];
      else if (n < NW + NL)  v = LW[(size_t)k*NL + (n - NW)];
    }
    tile[r4+rr][c] = v;
  }
  __syncthreads();
  #pragma unroll
  for (int rr = 0; rr < 32; rr += 8){
    int n = n0 + r4 + rr, k = k0 + c;
    if (n < Npad && k < K) BT[(size_t)n*K + k] = f2bf(tile[c][r4+rr]);
  }
}

// ---------------- 128^2 MFMA GEMM (layers 1,3): proven R3 structure ----------------
__global__ __launch_bounds__(256) void k_gemm(
    const ushort* __restrict__ A, const ushort* __restrict__ BT,
    ushort* __restrict__ Gatt, ushort* __restrict__ Skip,
    int K, int GW, int SW, int NCB, int CPX)
{
  __shared__ ushort As[128*64];
  __shared__ ushort Bs[128*64];
  const int bid = blockIdx.x;
  const int lb = CPX ? ((bid & 7)*CPX + (bid >> 3)) : bid;
  const size_t row0 = (size_t)(lb / NCB) * 128;
  const size_t col0 = (size_t)(lb % NCB) * 128;
  const int t = threadIdx.x;
  const int l = t & 63, w = t >> 6;
  const int wr = w >> 1, wc = w & 1;
  const int sr = l >> 3;
  const int sk = ((l & 7) ^ sr) << 3;
  const ushort* gA = A  + (row0 + w*8 + sr)*(size_t)K + sk;
  const ushort* gB = BT + (col0 + w*8 + sr)*(size_t)K + sk;
  ushort* lA = As + w*512;
  ushort* lB = Bs + w*512;
  const int rf = l & 15;
  const int g4 = l >> 4;
  f32x4 acc[4][4] = {};

  for (int k0 = 0; k0 < K; k0 += 64){
    #pragma unroll
    for (int i = 0; i < 4; ++i){
      gl_lds16(gA + k0 + (size_t)(i*32)*K, lA + i*2048);
      gl_lds16(gB + k0 + (size_t)(i*32)*K, lB + i*2048);
    }
    __syncthreads();
    #pragma unroll
    for (int kk = 0; kk < 2; ++kk){
      const int koff = ((((kk<<2) | g4) ^ (rf & 7)) << 3);
      bf16x8 af[4], bfr[4];
      #pragma unroll
      for (int i = 0; i < 4; ++i)
        af[i] = __builtin_bit_cast(bf16x8, *(const s16x8*)(As + (wr*64 + i*16 + rf)*64 + koff));
      #pragma unroll
      for (int j = 0; j < 4; ++j)
        bfr[j] = __builtin_bit_cast(bf16x8, *(const s16x8*)(Bs + (wc*64 + j*16 + rf)*64 + koff));
      #pragma unroll
      for (int i = 0; i < 4; ++i)
        #pragma unroll
        for (int j = 0; j < 4; ++j)
          acc[i][j] = __builtin_amdgcn_mfma_f32_16x16x32_bf16(af[i], bfr[j], acc[i][j], 0, 0, 0);
    }
    __syncthreads();
  }

  #pragma unroll
  for (int i = 0; i < 4; ++i){
    #pragma unroll
    for (int j = 0; j < 4; ++j){
      int gc = (int)col0 + wc*64 + j*16 + rf;
      #pragma unroll
      for (int r = 0; r < 4; ++r){
        size_t gr = row0 + wr*64 + i*16 + (g4<<2) + r;
        float v = acc[i][j][r];
        if (gc < GW)            Gatt[gr*GW + gc] = f2bf(v);
        else if (gc < GW + SW)  Skip[gr*SW + (gc - GW)] = f2bf(v);
      }
    }
  }
}

// ---------------- 8-phase 256^2 MFMA GEMM (layer 2, K multiple of 64, T>=3) --------
// 2 K-tile LDS double buffer (128 KiB), block-level C-quadrant per phase,
// 1 half-tile staged per phase, counted vmcnt(4) once per K-tile (never 0 except tail).
#define STG8(p0, hh, ktv, offU) do { \
  const ushort* _g = (p0) + (((size_t)(hh))<<7)*(size_t)K + (((size_t)(ktv))<<6); \
  gl_lds16(_g, S + (offU) + (w<<9)); \
  gl_lds16(_g + ((size_t)K<<6), S + (offU) + 4096 + (w<<9)); \
} while(0)

#define PHASE8(bb, mh, nh, ...) do { \
  const ushort* Ab = S + (bb)*32768 + (mh)*8192; \
  const ushort* Bb = S + (bb)*32768 + 16384 + (nh)*8192; \
  bf16x8 av[4][2], bv[2][2]; \
  _Pragma("unroll") \
  for (int i_ = 0; i_ < 4; ++i_){ \
    const int hr = wr*64 + i_*16 + rf; \
    const int sw = hr & 7; \
    av[i_][0] = *(const bf16x8*)(Ab + hr*64 + ((g4 ^ sw) << 3)); \
    av[i_][1] = *(const bf16x8*)(Ab + hr*64 + (((4|g4) ^ sw) << 3)); } \
  _Pragma("unroll") \
  for (int j_ = 0; j_ < 2; ++j_){ \
    const int cf = wc*32 + j_*16 + rf; \
    const int sw = cf & 7; \
    bv[j_][0] = *(const bf16x8*)(Bb + cf*64 + ((g4 ^ sw) << 3)); \
    bv[j_][1] = *(const bf16x8*)(Bb + cf*64 + (((4|g4) ^ sw) << 3)); } \
  __VA_ARGS__; \
  asm volatile("s_barrier" ::: "memory"); \
  __builtin_amdgcn_s_setprio(1); \
  _Pragma("unroll") \
  for (int kk_ = 0; kk_ < 2; ++kk_) \
    _Pragma("unroll") \
    for (int i_ = 0; i_ < 4; ++i_) \
      _Pragma("unroll") \
      for (int j_ = 0; j_ < 2; ++j_) \
        acc[mh][nh][i_][j_] = __builtin_amdgcn_mfma_f32_16x16x32_bf16( \
            av[i_][kk_], bv[j_][kk_], acc[mh][nh][i_][j_], 0, 0, 0); \
  __builtin_amdgcn_s_setprio(0); \
} while(0)

__global__ __launch_bounds__(512, 1) void k_gemm8(
    const ushort* __restrict__ A, const ushort* __restrict__ BT,
    ushort* __restrict__ Gatt, ushort* __restrict__ Skip,
    int K, int GW, int CPX)
{
  __shared__ ushort S[65536];                  // 128 KiB: 2 bufs x (A 32KB + B 32KB)
  const int bid = blockIdx.x;
  const int lb = (bid & 7)*CPX + (bid >> 3);   // XCD-chunked bijection (grid % 8 == 0)
  const size_t row0 = (size_t)(lb >> 3) * 256; // NCB = 8 col tiles
  const size_t col0 = (size_t)(lb & 7) * 256;
  const int t = threadIdx.x;
  const int l = t & 63, w = t >> 6;            // 8 waves
  const int wr = w >> 2, wc = w & 3;           // 2 x 4 wave grid
  const int rf = l & 15, g4 = l >> 4;
  const int T = K >> 6;

  // staging lane geometry: load0 covers rows [0,64), load1 rows [64,128) of a half
  const int r0 = t >> 3, s0 = t & 7;
  const ushort* pA = A  + (row0 + r0)*(size_t)K + ((s0 ^ (r0 & 7)) << 3);
  const ushort* pB = BT + (col0 + r0)*(size_t)K + ((s0 ^ (r0 & 7)) << 3);

  f32x4 acc[2][2][4][2] = {};

  // prologue: 4 halves of kt0 + A-lo/B-lo of kt1 (6 halves = 12 loads)
  STG8(pA, 0, 0, 0);
  STG8(pB, 0, 0, 16384);
  STG8(pA, 1, 0, 8192);
  STG8(pB, 1, 0, 24576);
  STG8(pA, 0, 1, 32768);
  STG8(pB, 0, 1, 49152);
  asm volatile("s_waitcnt vmcnt(4)");          // kt0's 4 halves complete; 2 in flight
  asm volatile("s_barrier" ::: "memory");

  for (int u = 0; u < T; ++u){
    const int b = u & 1;
    const int bbase = b << 15;                 // *32768
    const int nbase = bbase ^ 32768;
    const bool un1 = (u + 1 < T), un2 = (u + 2 < T);
    // p1: quadrant (Mlo,Nlo); stage A-hi(u+1)
    PHASE8(b, 0, 0, if (un1) STG8(pA, 1, u+1, nbase + 8192));
    asm volatile("s_barrier" ::: "memory");
    // p2: (Mlo,Nhi); stage B-hi(u+1)
    PHASE8(b, 0, 1, if (un1) STG8(pB, 1, u+1, nbase + 24576));
    asm volatile("s_barrier" ::: "memory");
    // p3: (Mhi,Nlo); stage A-lo(u+2) into this buffer (A-lo reads done at p2)
    PHASE8(b, 1, 0, if (un2) STG8(pA, 0, u+2, bbase));
    asm volatile("s_barrier" ::: "memory");
    // p4: (Mhi,Nhi); stage B-lo(u+2) (B-lo reads done at p3); counted wait
    PHASE8(b, 1, 1, if (un2) STG8(pB, 0, u+2, bbase + 16384));
    if (un2) asm volatile("s_waitcnt vmcnt(4)");
    else     asm volatile("s_waitcnt vmcnt(0)");
    asm volatile("s_barrier" ::: "memory");
  }

  ushort* outp; int cb;
  if ((int)col0 < GW){ outp = Gatt; cb = (int)col0; }
  else               { outp = Skip; cb = (int)col0 - GW; }
  #pragma unroll
  for (int mh = 0; mh < 2; ++mh)
    #pragma unroll
    for (int i = 0; i < 4; ++i)
      #pragma unroll
      for (int rr = 0; rr < 4; ++rr){
        size_t gr = row0 + mh*128 + wr*64 + i*16 + (g4<<2) + rr;
        ushort* rp = outp + gr*1024 + cb;
        #pragma unroll
        for (int nh = 0; nh < 2; ++nh)
          #pragma unroll
          for (int j = 0; j < 2; ++j)
            rp[nh*128 + wc*32 + j*16 + rf] = f2bf(acc[mh][nh][i][j][rr]);
      }
}

// ---------------- attention logits (layers 1-2: H=4, C=256) ----------------
__global__ __launch_bounds__(256) void k_al(const ushort* __restrict__ Gatt,
    const float* __restrict__ a_s, const float* __restrict__ a_d,
    float* __restrict__ als, float* __restrict__ ald, int N){
  int gw = (blockIdx.x*blockDim.x + threadIdx.x) >> 6;
  int l = threadIdx.x & 63;
  if (gw >= N) return;
  const ushort* row = Gatt + (size_t)gw*1024;
  int c0 = l*16;
  s16x8 v0 = *(const s16x8*)(row + c0);
  s16x8 v1 = *(const s16x8*)(row + c0 + 8);
  float ps = 0.f, pd = 0.f;
  #pragma unroll
  for (int q = 0; q < 8; ++q){
    float f0 = bf2f((ushort)v0[q]), f1 = bf2f((ushort)v1[q]);
    ps += f0*a_s[c0+q] + f1*a_s[c0+8+q];
    pd += f0*a_d[c0+q] + f1*a_d[c0+8+q];
  }
  #pragma unroll
  for (int off = 8; off; off >>= 1){
    ps += __shfl_down(ps, off);
    pd += __shfl_down(pd, off);
  }
  if ((l & 15) == 0){
    als[(size_t)gw*4 + (l>>4)] = ps;
    ald[(size_t)gw*4 + (l>>4)] = pd;
  }
}

// ---------------- softmax + aggregate + bias + skip + ELU (layers 1-2) ----------------
__global__ __launch_bounds__(256) void k_agg(
    const ushort* __restrict__ Gatt,
    const ushort* __restrict__ Skip,
    const float*  __restrict__ als,
    const float*  __restrict__ ald,
    const float*  __restrict__ bias,
    const float*  __restrict__ lbias,
    const int*    __restrict__ indptr,
    const int*    __restrict__ csrc,
    const float*  __restrict__ cew,
    ushort* __restrict__ Hout,
    int N)
{
  const int n = blockIdx.x;
  const int t = threadIdx.x;
  if (n >= N){
    ushort4 z = {0,0,0,0};
    *(ushort4*)(Hout + (size_t)n*1024 + t*4) = z;
    return;
  }
  const int l = t & 63, w = t >> 6;
  const int beg = indptr[n];
  const int deg = indptr[n+1] - beg;
  __shared__ float s_ald[4], s_m[4], s_den[4];
  __shared__ int   s_src[64];
  __shared__ float s_w[64][4];
  __shared__ float s_part[3][64][16];
  if (t < 4) s_ald[t] = ald[(size_t)n*4 + t];
  __syncthreads();
  const bool fast = (deg <= 64);

  if (fast){
    int e2 = t >> 2, hh = t & 3;
    if (e2 < deg){
      int s = csrc[beg + e2];
      if (hh == 0) s_src[e2] = s;
      float r_ = als[(size_t)s*4 + hh] + s_ald[hh];
      s_w[e2][hh] = r_ > 0.f ? r_ : 0.2f*r_;
    }
    __syncthreads();
    float mye = (l < deg) ? s_w[l][w] : -1e30f;
    float mx = mye;
    #pragma unroll
    for (int o = 32; o; o >>= 1) mx = fmaxf(mx, __shfl_xor(mx, o));
    float ex = (l < deg) ? __expf(mye - mx) : 0.f;
    float den = ex;
    #pragma unroll
    for (int o = 32; o; o >>= 1) den += __shfl_xor(den, o);
    den += 1e-16f;
    if (l < deg) s_w[l][w] = ex / den * cew[beg + l];
    __syncthreads();
  } else {
    const float aldh = s_ald[w];
    float mx = -1e30f;
    for (int i = l; i < deg; i += 64){
      int s = csrc[beg+i];
      float e = als[(size_t)s*4 + w] + aldh;
      e = e > 0.f ? e : 0.2f*e;
      mx = fmaxf(mx, e);
    }
    #pragma unroll
    for (int off = 32; off; off >>= 1) mx = fmaxf(mx, __shfl_xor(mx, off));
    if (l == 0) s_m[w] = mx;
    __syncthreads();
    const float mh = s_m[w];
    float den = 0.f;
    for (int i = l; i < deg; i += 64){
      int s = csrc[beg+i];
      float e = als[(size_t)s*4 + w] + aldh;
      e = e > 0.f ? e : 0.2f*e;
      den += __expf(e - mh);
    }
    #pragma unroll
    for (int off = 32; off; off >>= 1) den += __shfl_xor(den, off);
    if (l == 0) s_den[w] = den + 1e-16f;
    __syncthreads();
  }

  const int h2 = l >> 4;
  const ushort* gbase = Gatt + (size_t)l*16;
  float a[16];
  #pragma unroll
  for (int q = 0; q < 16; ++q) a[q] = 0.f;
  for (int c0 = 0; c0 < deg; c0 += 64){
    int nc = min(64, deg - c0);
    if (!fast){
      int ei2 = t >> 2, hh = t & 3;
      if (ei2 < nc){
        int s = csrc[beg + c0 + ei2];
        if (hh == 0) s_src[ei2] = s;
        float e = als[(size_t)s*4 + hh] + s_ald[hh];
        e = e > 0.f ? e : 0.2f*e;
        s_w[ei2][hh] = __expf(e - s_m[hh]) / s_den[hh] * cew[beg + c0 + ei2];
      }
      __syncthreads();
    }
    for (int j = w; j < nc; j += 4){
      int s = s_src[j];
      float wg = s_w[j][h2];
      const ushort* rp = gbase + (size_t)s*1024;
      s16x8 h0 = *(const s16x8*)rp;
      s16x8 h1 = *(const s16x8*)(rp + 8);
      #pragma unroll
      for (int q = 0; q < 8; ++q) a[q] += wg * bf2f((ushort)h0[q]);
      #pragma unroll
      for (int q = 0; q < 8; ++q) a[q+8] += wg * bf2f((ushort)h1[q]);
    }
    __syncthreads();
  }
  if (w){
    #pragma unroll
    for (int q = 0; q < 16; ++q) s_part[w-1][l][q] = a[q];
  }
  __syncthreads();
  if (w == 0){
    #pragma unroll
    for (int q = 0; q < 16; ++q) a[q] += s_part[0][l][q] + s_part[1][l][q] + s_part[2][l][q];
    const int col = l*16;
    s16x8 sk0 = *(const s16x8*)(Skip + (size_t)n*1024 + col);
    s16x8 sk1 = *(const s16x8*)(Skip + (size_t)n*1024 + col + 8);
    s16x8 ov0, ov1;
    #pragma unroll
    for (int q = 0; q < 8; ++q){
      float v = a[q] + bias[col+q] + lbias[col+q] + bf2f((ushort)sk0[q]);
      v = v > 0.f ? v : __expf(v) - 1.f;
      ov0[q] = (short)f2bf(v);
      float v2 = a[q+8] + bias[col+8+q] + lbias[col+8+q] + bf2f((ushort)sk1[q]);
      v2 = v2 > 0.f ? v2 : __expf(v2) - 1.f;
      ov1[q] = (short)f2bf(v2);
    }
    *(s16x8*)(Hout + (size_t)n*1024 + col)     = ov0;
    *(s16x8*)(Hout + (size_t)n*1024 + col + 8) = ov1;
  }
}

// ---------------- layer 3: logits (H=6, C=10) ----------------
__global__ void k_al3(const ushort* __restrict__ G3, const float* __restrict__ a_s,
                      const float* __restrict__ a_d,
                      float* __restrict__ als, float* __restrict__ ald, int N){
  int n = blockIdx.x*256 + threadIdx.x;
  if (n >= N) return;
  const ushort* row = G3 + (size_t)n*60;
  #pragma unroll
  for (int h = 0; h < 6; ++h){
    float ps = 0.f, pd = 0.f;
    #pragma unroll
    for (int c = 0; c < 10; ++c){
      float v = bf2f(row[h*10 + c]);
      ps += v * a_s[h*10 + c];
      pd += v * a_d[h*10 + c];
    }
    als[(size_t)n*6 + h] = ps;
    ald[(size_t)n*6 + h] = pd;
  }
}

// ---------------- layer 3: edge-parallel online softmax + aggregate + mean ----------------
__global__ __launch_bounds__(64) void k_agg3(
    const ushort* __restrict__ G3,
    const ushort* __restrict__ Skip3,
    const float*  __restrict__ als,
    const float*  __restrict__ ald,
    const float*  __restrict__ b3,
    const float*  __restrict__ lb3,
    const int*    __restrict__ indptr,
    const int*    __restrict__ csrc,
    const float*  __restrict__ cew,
    float* __restrict__ out, int N)
{
  const int n = blockIdx.x;
  const int l = threadIdx.x;
  const int beg = indptr[n], deg = indptr[n+1] - beg;
  __shared__ float s_aldh[6];
  __shared__ int   s_src[64];
  __shared__ float s_wgt[64][6];
  __shared__ float s_o[6][10];
  if (l < 6) s_aldh[l] = ald[(size_t)n*6 + l];
  __syncthreads();
  float m0=-1e30f,m1=-1e30f,m2=-1e30f,m3=-1e30f,m4=-1e30f,m5=-1e30f;
  float d0=0.f,d1=0.f,d2=0.f,d3=0.f,d4=0.f,d5=0.f;
  for (int c0 = 0; c0 < deg; c0 += 64){
    int nc = min(64, deg - c0);
    bool act = l < nc;
    int s = act ? csrc[beg + c0 + l] : 0;
#define HP(hh, mm, dd) { \
    float e = -1e30f; \
    if (act){ float r_ = als[(size_t)s*6 + hh] + s_aldh[hh]; e = r_ > 0.f ? r_ : 0.2f*r_; } \
    float cm = e; \
    for (int o_ = 32; o_; o_ >>= 1) cm = fmaxf(cm, __shfl_xor(cm, o_)); \
    float nm = fmaxf(mm, cm); \
    float ex = act ? __expf(e - nm) : 0.f; \
    for (int o_ = 32; o_; o_ >>= 1) ex += __shfl_xor(ex, o_); \
    dd = dd * __expf(mm - nm) + ex; mm = nm; }
    HP(0,m0,d0) HP(1,m1,d1) HP(2,m2,d2) HP(3,m3,d3) HP(4,m4,d4) HP(5,m5,d5)
#undef HP
  }
  const int h = l / 10, c = l % 10;
  float o = 0.f;
  for (int c0 = 0; c0 < deg; c0 += 64){
    int nc = min(64, deg - c0);
    if (l < nc){
      int s = csrc[beg + c0 + l];
      s_src[l] = s;
      float w_ = cew[beg + c0 + l];
#define WP(hh, mm, dd) { \
      float r_ = als[(size_t)s*6 + hh] + s_aldh[hh]; \
      float e = r_ > 0.f ? r_ : 0.2f*r_; \
      s_wgt[l][hh] = __expf(e - mm) / (dd + 1e-16f) * w_; }
      WP(0,m0,d0) WP(1,m1,d1) WP(2,m2,d2) WP(3,m3,d3) WP(4,m4,d4) WP(5,m5,d5)
#undef WP
    }
    __syncthreads();
    if (l < 60){
      for (int i = 0; i < nc; ++i)
        o += s_wgt[i][h] * bf2f(G3[(size_t)s_src[i]*60 + l]);
    }
    __syncthreads();
  }
  if (l < 60) s_o[h][c] = o;
  __syncthreads();
  if (l < 10){
    float v = (s_o[0][l]+s_o[1][l]+s_o[2][l]+s_o[3][l]+s_o[4][l]+s_o[5][l]) * (1.0f/6.0f);
    v += b3[l] + lb3[l] + bf2f(Skip3[(size_t)n*10 + l]);
    out[(size_t)n*10 + l] = v;
  }
}

// ---------------- host ----------------
extern "C" void kernel_launch(void* const* d_in, const int* in_sizes, int n_in,
                              void* d_out, int out_size, void* d_ws, size_t ws_size,
                              hipStream_t stream)
{
  const int N = 20000, F = 128, E = 320000, ET = E + N;
  const int Mpad = 20224;            // 79*256 = 158*128
  const int F1 = 1024, NT = 2048;
  const int NWG1 = (Mpad/128)*(NT/128);   // 158*16 = 2528, %8==0
  const int NWG2 = (Mpad/256)*(NT/256);   // 79*8  = 632,  %8==0

  const float* x   = (const float*)d_in[0];
  const int*   ei  = (const int*)  d_in[1];
  const float* ew  = (const float*)d_in[2];
  const float* W1  = (const float*)d_in[3];
  const float* a1s = (const float*)d_in[4];
  const float* a1d = (const float*)d_in[5];
  const float* b1  = (const float*)d_in[6];
  const float* lw1 = (const float*)d_in[7];
  const float* lb1 = (const float*)d_in[8];
  const float* W2  = (const float*)d_in[9];
  const float* a2s = (const float*)d_in[10];
  const float* a2d = (const float*)d_in[11];
  const float* b2  = (const float*)d_in[12];
  const float* lw2 = (const float*)d_in[13];
  const float* lb2 = (const float*)d_in[14];
  const float* W3  = (const float*)d_in[15];
  const float* a3s = (const float*)d_in[16];
  const float* a3d = (const float*)d_in[17];
  const float* b3  = (const float*)d_in[18];
  const float* lw3 = (const float*)d_in[19];
  const float* lb3 = (const float*)d_in[20];

  char* ws = (char*)d_ws;
  size_t off = 0;
  auto alloc = [&](size_t bytes) -> void* {
    void* p = ws + off;
    off = (off + bytes + 255) & ~(size_t)255;
    return p;
  };
  ushort* Gatt = (ushort*)alloc((size_t)Mpad*F1*2);
  ushort* Skip = (ushort*)alloc((size_t)Mpad*F1*2);
  ushort* H    = (ushort*)alloc((size_t)Mpad*F1*2);
  ushort* xb   = (ushort*)alloc((size_t)Mpad*F*2);
  ushort* BT   = (ushort*)alloc((size_t)NT*1024*2);
  float*  als  = (float*) alloc((size_t)N*6*4);
  float*  ald  = (float*) alloc((size_t)N*6*4);
  int*    counts = (int*)alloc((size_t)2*N*4);
  int*    cursor = counts + N;
  int*    indptr = (int*)alloc((size_t)(N+1)*4);
  int*    csrc   = (int*)alloc((size_t)ET*4);
  float*  cew    = (float*)alloc((size_t)ET*4);
  if (off > ws_size) return;

  hipMemsetAsync(counts, 0, (size_t)2*N*4, stream);
  k_count<<<(ET+255)/256, 256, 0, stream>>>(ei, counts, E, ET);
  k_scan<<<1, 1024, 0, stream>>>(counts, indptr, N);
  k_fill<<<(ET+255)/256, 256, 0, stream>>>(ei, ew, indptr, cursor, csrc, cew, E, ET);
  k_f2b<<<(Mpad*F/8+255)/256, 256, 0, stream>>>(x, xb, N*F/8, Mpad*F/8);

  // ---- layer 1 (128^2 path) ----
  k_packB<<<dim3((F+31)/32, NT/32), 256, 0, stream>>>(W1, lw1, BT, F, 1024, 1024, NT);
  k_gemm<<<dim3(NWG1), 256, 0, stream>>>(xb, BT, Gatt, Skip, F, 1024, 1024, NT/128, NWG1/8);
  k_al<<<(N+3)/4, 256, 0, stream>>>(Gatt, a1s, a1d, als, ald, N);
  k_agg<<<Mpad, 256, 0, stream>>>(Gatt, Skip, als, ald, b1, lb1, indptr, csrc, cew, H, N);

  // ---- layer 2 (8-phase 256^2 path) ----
  k_packB<<<dim3(F1/32, NT/32), 256, 0, stream>>>(W2, lw2, BT, F1, 1024, 1024, NT);
  k_gemm8<<<dim3(NWG2), 512, 0, stream>>>(H, BT, Gatt, Skip, F1, 1024, NWG2/8);
  k_al<<<(N+3)/4, 256, 0, stream>>>(Gatt, a2s, a2d, als, ald, N);
  k_agg<<<Mpad, 256, 0, stream>>>(Gatt, Skip, als, ald, b2, lb2, indptr, csrc, cew, H, N);

  // ---- layer 3 (128^2 path) ----
  k_packB<<<dim3(F1/32, 128/32), 256, 0, stream>>>(W3, lw3, BT, F1, 60, 10, 128);
  k_gemm<<<dim3(Mpad/128), 256, 0, stream>>>(H, BT, Gatt, Skip, F1, 60, 10, 1, 0);
  k_al3<<<(N+255)/256, 256, 0, stream>>>(Gatt, a3s, a3d, als, ald, N);
  k_agg3<<<N, 64, 0, stream>>>(Gatt, Skip, als, ald, b3, lb3, indptr, csrc, cew,
                               (float*)d_out, N);
}

// Round 7
// 503.888 us; speedup vs baseline: 1.0278x; 1.0278x over previous
//
#include <hip/hip_runtime.h>

typedef __attribute__((ext_vector_type(8))) short s16x8;
typedef __attribute__((ext_vector_type(8))) __bf16 bf16x8;
typedef __attribute__((ext_vector_type(4))) float f32x4;

__device__ inline float bf2f(ushort u){ return __uint_as_float(((unsigned)u)<<16); }
__device__ inline ushort f2bf(float f){
  unsigned u = __float_as_uint(f);
  unsigned r = (u + 0x7fffu + ((u>>16)&1u)) >> 16;
  return (ushort)r;
}

__device__ inline void gl_lds16(const ushort* g, ushort* l){
  __builtin_amdgcn_global_load_lds(
      (const __attribute__((address_space(1))) unsigned int*)g,
      (__attribute__((address_space(3))) unsigned int*)l,
      16, 0, 0);
}

// ---------------- CSR build ----------------
__global__ void k_count(const int* __restrict__ ei, int* __restrict__ counts,
                        int E, int ET){
  int e = blockIdx.x*256 + threadIdx.x;
  if (e >= ET) return;
  int dst = (e < E) ? ei[E + e] : (e - E);
  atomicAdd(&counts[dst], 1);
}

__global__ __launch_bounds__(1024) void k_scan(const int* __restrict__ cnt,
                                               int* __restrict__ indptr, int N){
  __shared__ int part[1024];
  int t = threadIdx.x;
  int per = (N + 1023) / 1024;
  int base = t * per;
  int s = 0;
  for (int i = 0; i < per; ++i){ int idx = base + i; if (idx < N) s += cnt[idx]; }
  part[t] = s; __syncthreads();
  for (int off = 1; off < 1024; off <<= 1){
    int v = (t >= off) ? part[t-off] : 0;
    __syncthreads();
    if (t >= off) part[t] += v;
    __syncthreads();
  }
  int run = (t == 0) ? 0 : part[t-1];
  for (int i = 0; i < per; ++i){
    int idx = base + i;
    if (idx < N){ indptr[idx] = run; run += cnt[idx]; }
  }
  if (t == 1023) indptr[N] = run;
}

__global__ void k_fill(const int* __restrict__ ei, const float* __restrict__ ew,
                       const int* __restrict__ indptr, int* __restrict__ cursor,
                       int* __restrict__ csrc, float* __restrict__ cew,
                       int E, int ET){
  int e = blockIdx.x*256 + threadIdx.x;
  if (e >= ET) return;
  int src, dst; float w;
  if (e < E){ src = ei[e]; dst = ei[E + e]; w = ew[e]; }
  else { src = dst = e - E; w = 1.0f; }
  int pos = indptr[dst] + atomicAdd(&cursor[dst], 1);
  csrc[pos] = src; cew[pos] = w;
}

// ---------------- conversions / packing ----------------
__global__ void k_f2b(const float* __restrict__ x, ushort* __restrict__ xb,
                      int n8valid, int n8total){
  int i = blockIdx.x*256 + threadIdx.x;
  if (i >= n8total) return;
  s16x8 o = {0,0,0,0,0,0,0,0};
  if (i < n8valid){
    const float4* p = (const float4*)x + (size_t)i*2;
    float4 a = p[0], b = p[1];
    o[0]=(short)f2bf(a.x); o[1]=(short)f2bf(a.y); o[2]=(short)f2bf(a.z); o[3]=(short)f2bf(a.w);
    o[4]=(short)f2bf(b.x); o[5]=(short)f2bf(b.y); o[6]=(short)f2bf(b.z); o[7]=(short)f2bf(b.w);
  }
  *((s16x8*)xb + i) = o;
}

__global__ __launch_bounds__(256) void k_packB(
    const float* __restrict__ W, const float* __restrict__ LW,
    ushort* __restrict__ BT, int K, int NW, int NL, int Npad)
{
  __shared__ float tile[32][33];
  int k0 = blockIdx.x*32, n0 = blockIdx.y*32;
  int c = threadIdx.x & 31, r4 = threadIdx.x >> 5;
  #pragma unroll
  for (int rr = 0; rr < 32; rr += 8){
    int k = k0 + r4 + rr, n = n0 + c;
    float v = 0.f;
    if (k < K){
      if (n < NW)            v = W[(size_t)k*NW + n];
      else if (n < NW + NL)  v = LW[(size_t)k*NL + (n - NW)];
    }
    tile[r4+rr][c] = v;
  }
  __syncthreads();
  #pragma unroll
  for (int rr = 0; rr < 32; rr += 8){
    int n = n0 + r4 + rr, k = k0 + c;
    if (n < Npad && k < K) BT[(size_t)n*K + k] = f2bf(tile[c][r4+rr]);
  }
}

// ---------------- 128^2 MFMA GEMM (layers 1,3): proven R3 structure ----------------
__global__ __launch_bounds__(256) void k_gemm(
    const ushort* __restrict__ A, const ushort* __restrict__ BT,
    ushort* __restrict__ Gatt, ushort* __restrict__ Skip,
    int K, int GW, int SW, int NCB, int CPX)
{
  __shared__ ushort As[128*64];
  __shared__ ushort Bs[128*64];
  const int bid = blockIdx.x;
  const int lb = CPX ? ((bid & 7)*CPX + (bid >> 3)) : bid;
  const size_t row0 = (size_t)(lb / NCB) * 128;
  const size_t col0 = (size_t)(lb % NCB) * 128;
  const int t = threadIdx.x;
  const int l = t & 63, w = t >> 6;
  const int wr = w >> 1, wc = w & 1;
  const int sr = l >> 3;
  const int sk = ((l & 7) ^ sr) << 3;
  const ushort* gA = A  + (row0 + w*8 + sr)*(size_t)K + sk;
  const ushort* gB = BT + (col0 + w*8 + sr)*(size_t)K + sk;
  ushort* lA = As + w*512;
  ushort* lB = Bs + w*512;
  const int rf = l & 15;
  const int g4 = l >> 4;
  f32x4 acc[4][4] = {};

  for (int k0 = 0; k0 < K; k0 += 64){
    #pragma unroll
    for (int i = 0; i < 4; ++i){
      gl_lds16(gA + k0 + (size_t)(i*32)*K, lA + i*2048);
      gl_lds16(gB + k0 + (size_t)(i*32)*K, lB + i*2048);
    }
    __syncthreads();
    #pragma unroll
    for (int kk = 0; kk < 2; ++kk){
      const int koff = ((((kk<<2) | g4) ^ (rf & 7)) << 3);
      bf16x8 af[4], bfr[4];
      #pragma unroll
      for (int i = 0; i < 4; ++i)
        af[i] = __builtin_bit_cast(bf16x8, *(const s16x8*)(As + (wr*64 + i*16 + rf)*64 + koff));
      #pragma unroll
      for (int j = 0; j < 4; ++j)
        bfr[j] = __builtin_bit_cast(bf16x8, *(const s16x8*)(Bs + (wc*64 + j*16 + rf)*64 + koff));
      #pragma unroll
      for (int i = 0; i < 4; ++i)
        #pragma unroll
        for (int j = 0; j < 4; ++j)
          acc[i][j] = __builtin_amdgcn_mfma_f32_16x16x32_bf16(af[i], bfr[j], acc[i][j], 0, 0, 0);
    }
    __syncthreads();
  }

  #pragma unroll
  for (int i = 0; i < 4; ++i){
    #pragma unroll
    for (int j = 0; j < 4; ++j){
      int gc = (int)col0 + wc*64 + j*16 + rf;
      #pragma unroll
      for (int r = 0; r < 4; ++r){
        size_t gr = row0 + wr*64 + i*16 + (g4<<2) + r;
        float v = acc[i][j][r];
        if (gc < GW)            Gatt[gr*GW + gc] = f2bf(v);
        else if (gc < GW + SW)  Skip[gr*SW + (gc - GW)] = f2bf(v);
      }
    }
  }
}

// ---------------- 8-phase 256^2 MFMA GEMM v2: fragment reuse (layer 2) ----------------
// Same sync/staging skeleton as verified v1; quadrant order Q00->Q01->Q11->Q10 with
// fragments kept in registers: ds_read_b128 per K-tile 48 -> 24 (12,4,8,0 per phase).
#define STG8(p0, hh, ktv, offU) do { \
  const ushort* _g = (p0) + (((size_t)(hh))<<7)*(size_t)K + (((size_t)(ktv))<<6); \
  gl_lds16(_g, S + (offU) + (w<<9)); \
  gl_lds16(_g + ((size_t)K<<6), S + (offU) + 4096 + (w<<9)); \
} while(0)

#define RD_A(base_) do { _Pragma("unroll") \
  for (int i_ = 0; i_ < 4; ++i_){ \
    const int hr = wr*64 + i_*16 + rf; const int sw = hr & 7; \
    av[i_][0] = *(const bf16x8*)((base_) + hr*64 + ((g4 ^ sw) << 3)); \
    av[i_][1] = *(const bf16x8*)((base_) + hr*64 + (((4|g4) ^ sw) << 3)); } \
} while(0)

#define RD_B(base_, dst_) do { _Pragma("unroll") \
  for (int j_ = 0; j_ < 2; ++j_){ \
    const int cf = wc*32 + j_*16 + rf; const int sw = cf & 7; \
    dst_[j_][0] = *(const bf16x8*)((base_) + cf*64 + ((g4 ^ sw) << 3)); \
    dst_[j_][1] = *(const bf16x8*)((base_) + cf*64 + (((4|g4) ^ sw) << 3)); } \
} while(0)

#define MM8(mh, nh, bv_) do { \
  asm volatile("s_barrier" ::: "memory"); \
  __builtin_amdgcn_s_setprio(1); \
  _Pragma("unroll") \
  for (int kk_ = 0; kk_ < 2; ++kk_) \
    _Pragma("unroll") \
    for (int i_ = 0; i_ < 4; ++i_) \
      _Pragma("unroll") \
      for (int j_ = 0; j_ < 2; ++j_) \
        acc[mh][nh][i_][j_] = __builtin_amdgcn_mfma_f32_16x16x32_bf16( \
            av[i_][kk_], bv_[j_][kk_], acc[mh][nh][i_][j_], 0, 0, 0); \
  __builtin_amdgcn_s_setprio(0); \
} while(0)

__global__ __launch_bounds__(512, 1) void k_gemm8(
    const ushort* __restrict__ A, const ushort* __restrict__ BT,
    ushort* __restrict__ Gatt, ushort* __restrict__ Skip,
    int K, int GW, int CPX)
{
  __shared__ ushort S[65536];                  // 128 KiB: 2 bufs x (A 32KB + B 32KB)
  const int bid = blockIdx.x;
  const int lb = (bid & 7)*CPX + (bid >> 3);   // XCD-chunked bijection (grid % 8 == 0)
  const size_t row0 = (size_t)(lb >> 3) * 256; // NCB = 8 col tiles
  const size_t col0 = (size_t)(lb & 7) * 256;
  const int t = threadIdx.x;
  const int l = t & 63, w = t >> 6;            // 8 waves
  const int wr = w >> 2, wc = w & 3;           // 2 x 4 wave grid
  const int rf = l & 15, g4 = l >> 4;
  const int T = K >> 6;

  const int r0 = t >> 3, s0 = t & 7;
  const ushort* pA = A  + (row0 + r0)*(size_t)K + ((s0 ^ (r0 & 7)) << 3);
  const ushort* pB = BT + (col0 + r0)*(size_t)K + ((s0 ^ (r0 & 7)) << 3);

  f32x4 acc[2][2][4][2] = {};
  bf16x8 av[4][2], bvlo[2][2], bvhi[2][2];

  // prologue: 4 halves of kt0 + A-lo/B-lo of kt1 (12 loads)
  STG8(pA, 0, 0, 0);
  STG8(pB, 0, 0, 16384);
  STG8(pA, 1, 0, 8192);
  STG8(pB, 1, 0, 24576);
  STG8(pA, 0, 1, 32768);
  STG8(pB, 0, 1, 49152);
  asm volatile("s_waitcnt vmcnt(4)");          // kt0's 4 halves complete; 2 in flight
  asm volatile("s_barrier" ::: "memory");

  for (int u = 0; u < T; ++u){
    const int b = u & 1;
    const int bbase = b << 15;
    const int nbase = bbase ^ 32768;
    const bool un1 = (u + 1 < T), un2 = (u + 2 < T);
    const ushort* Alo = S + bbase;
    const ushort* Ahi = S + bbase + 8192;
    const ushort* Blo = S + bbase + 16384;
    const ushort* Bhi = S + bbase + 24576;
    // p1: Q00 — read A-lo + B-lo; stage A-hi(u+1)
    RD_A(Alo); RD_B(Blo, bvlo);
    if (un1) STG8(pA, 1, u+1, nbase + 8192);
    MM8(0, 0, bvlo);
    asm volatile("s_barrier" ::: "memory");
    // p2: Q01 — read B-hi (A kept); stage B-hi(u+1)
    RD_B(Bhi, bvhi);
    if (un1) STG8(pB, 1, u+1, nbase + 24576);
    MM8(0, 1, bvhi);
    asm volatile("s_barrier" ::: "memory");
    // p3: Q11 — read A-hi (B-hi kept); stage A-lo(u+2) (A-lo last read p1)
    RD_A(Ahi);
    if (un2) STG8(pA, 0, u+2, bbase);
    MM8(1, 1, bvhi);
    asm volatile("s_barrier" ::: "memory");
    // p4: Q10 — no reads (A-hi + B-lo kept); stage B-lo(u+2); counted wait
    if (un2) STG8(pB, 0, u+2, bbase + 16384);
    MM8(1, 0, bvlo);
    if (un2) asm volatile("s_waitcnt vmcnt(4)");
    else     asm volatile("s_waitcnt vmcnt(0)");
    asm volatile("s_barrier" ::: "memory");
  }

  ushort* outp; int cb;
  if ((int)col0 < GW){ outp = Gatt; cb = (int)col0; }
  else               { outp = Skip; cb = (int)col0 - GW; }
  #pragma unroll
  for (int mh = 0; mh < 2; ++mh)
    #pragma unroll
    for (int i = 0; i < 4; ++i)
      #pragma unroll
      for (int rr = 0; rr < 4; ++rr){
        size_t gr = row0 + mh*128 + wr*64 + i*16 + (g4<<2) + rr;
        ushort* rp = outp + gr*1024 + cb;
        #pragma unroll
        for (int nh = 0; nh < 2; ++nh)
          #pragma unroll
          for (int j = 0; j < 2; ++j)
            rp[nh*128 + wc*32 + j*16 + rf] = f2bf(acc[mh][nh][i][j][rr]);
      }
}

// ---------------- attention logits (layers 1-2: H=4, C=256) ----------------
__global__ __launch_bounds__(256) void k_al(const ushort* __restrict__ Gatt,
    const float* __restrict__ a_s, const float* __restrict__ a_d,
    float* __restrict__ als, float* __restrict__ ald, int N){
  int gw = (blockIdx.x*blockDim.x + threadIdx.x) >> 6;
  int l = threadIdx.x & 63;
  if (gw >= N) return;
  const ushort* row = Gatt + (size_t)gw*1024;
  int c0 = l*16;
  s16x8 v0 = *(const s16x8*)(row + c0);
  s16x8 v1 = *(const s16x8*)(row + c0 + 8);
  float ps = 0.f, pd = 0.f;
  #pragma unroll
  for (int q = 0; q < 8; ++q){
    float f0 = bf2f((ushort)v0[q]), f1 = bf2f((ushort)v1[q]);
    ps += f0*a_s[c0+q] + f1*a_s[c0+8+q];
    pd += f0*a_d[c0+q] + f1*a_d[c0+8+q];
  }
  #pragma unroll
  for (int off = 8; off; off >>= 1){
    ps += __shfl_down(ps, off);
    pd += __shfl_down(pd, off);
  }
  if ((l & 15) == 0){
    als[(size_t)gw*4 + (l>>4)] = ps;
    ald[(size_t)gw*4 + (l>>4)] = pd;
  }
}

// ---------------- softmax + aggregate + bias + skip + ELU (layers 1-2) ----------------
__global__ __launch_bounds__(256) void k_agg(
    const ushort* __restrict__ Gatt,
    const ushort* __restrict__ Skip,
    const float*  __restrict__ als,
    const float*  __restrict__ ald,
    const float*  __restrict__ bias,
    const float*  __restrict__ lbias,
    const int*    __restrict__ indptr,
    const int*    __restrict__ csrc,
    const float*  __restrict__ cew,
    ushort* __restrict__ Hout,
    int N)
{
  const int n = blockIdx.x;
  const int t = threadIdx.x;
  if (n >= N){
    ushort4 z = {0,0,0,0};
    *(ushort4*)(Hout + (size_t)n*1024 + t*4) = z;
    return;
  }
  const int l = t & 63, w = t >> 6;
  const int beg = indptr[n];
  const int deg = indptr[n+1] - beg;
  __shared__ float s_ald[4], s_m[4], s_den[4];
  __shared__ int   s_src[64];
  __shared__ float s_w[64][4];
  __shared__ float s_part[3][64][16];
  if (t < 4) s_ald[t] = ald[(size_t)n*4 + t];
  __syncthreads();
  const bool fast = (deg <= 64);

  if (fast){
    int e2 = t >> 2, hh = t & 3;
    if (e2 < deg){
      int s = csrc[beg + e2];
      if (hh == 0) s_src[e2] = s;
      float r_ = als[(size_t)s*4 + hh] + s_ald[hh];
      s_w[e2][hh] = r_ > 0.f ? r_ : 0.2f*r_;
    }
    __syncthreads();
    float mye = (l < deg) ? s_w[l][w] : -1e30f;
    float mx = mye;
    #pragma unroll
    for (int o = 32; o; o >>= 1) mx = fmaxf(mx, __shfl_xor(mx, o));
    float ex = (l < deg) ? __expf(mye - mx) : 0.f;
    float den = ex;
    #pragma unroll
    for (int o = 32; o; o >>= 1) den += __shfl_xor(den, o);
    den += 1e-16f;
    if (l < deg) s_w[l][w] = ex / den * cew[beg + l];
    __syncthreads();
  } else {
    const float aldh = s_ald[w];
    float mx = -1e30f;
    for (int i = l; i < deg; i += 64){
      int s = csrc[beg+i];
      float e = als[(size_t)s*4 + w] + aldh;
      e = e > 0.f ? e : 0.2f*e;
      mx = fmaxf(mx, e);
    }
    #pragma unroll
    for (int off = 32; off; off >>= 1) mx = fmaxf(mx, __shfl_xor(mx, off));
    if (l == 0) s_m[w] = mx;
    __syncthreads();
    const float mh = s_m[w];
    float den = 0.f;
    for (int i = l; i < deg; i += 64){
      int s = csrc[beg+i];
      float e = als[(size_t)s*4 + w] + aldh;
      e = e > 0.f ? e : 0.2f*e;
      den += __expf(e - mh);
    }
    #pragma unroll
    for (int off = 32; off; off >>= 1) den += __shfl_xor(den, off);
    if (l == 0) s_den[w] = den + 1e-16f;
    __syncthreads();
  }

  const int h2 = l >> 4;
  const ushort* gbase = Gatt + (size_t)l*16;
  float a[16];
  #pragma unroll
  for (int q = 0; q < 16; ++q) a[q] = 0.f;
  for (int c0 = 0; c0 < deg; c0 += 64){
    int nc = min(64, deg - c0);
    if (!fast){
      int ei2 = t >> 2, hh = t & 3;
      if (ei2 < nc){
        int s = csrc[beg + c0 + ei2];
        if (hh == 0) s_src[ei2] = s;
        float e = als[(size_t)s*4 + hh] + s_ald[hh];
        e = e > 0.f ? e : 0.2f*e;
        s_w[ei2][hh] = __expf(e - s_m[hh]) / s_den[hh] * cew[beg + c0 + ei2];
      }
      __syncthreads();
    }
    for (int j = w; j < nc; j += 4){
      int s = s_src[j];
      float wg = s_w[j][h2];
      const ushort* rp = gbase + (size_t)s*1024;
      s16x8 h0 = *(const s16x8*)rp;
      s16x8 h1 = *(const s16x8*)(rp + 8);
      #pragma unroll
      for (int q = 0; q < 8; ++q) a[q] += wg * bf2f((ushort)h0[q]);
      #pragma unroll
      for (int q = 0; q < 8; ++q) a[q+8] += wg * bf2f((ushort)h1[q]);
    }
    __syncthreads();
  }
  if (w){
    #pragma unroll
    for (int q = 0; q < 16; ++q) s_part[w-1][l][q] = a[q];
  }
  __syncthreads();
  if (w == 0){
    #pragma unroll
    for (int q = 0; q < 16; ++q) a[q] += s_part[0][l][q] + s_part[1][l][q] + s_part[2][l][q];
    const int col = l*16;
    s16x8 sk0 = *(const s16x8*)(Skip + (size_t)n*1024 + col);
    s16x8 sk1 = *(const s16x8*)(Skip + (size_t)n*1024 + col + 8);
    s16x8 ov0, ov1;
    #pragma unroll
    for (int q = 0; q < 8; ++q){
      float v = a[q] + bias[col+q] + lbias[col+q] + bf2f((ushort)sk0[q]);
      v = v > 0.f ? v : __expf(v) - 1.f;
      ov0[q] = (short)f2bf(v);
      float v2 = a[q+8] + bias[col+8+q] + lbias[col+8+q] + bf2f((ushort)sk1[q]);
      v2 = v2 > 0.f ? v2 : __expf(v2) - 1.f;
      ov1[q] = (short)f2bf(v2);
    }
    *(s16x8*)(Hout + (size_t)n*1024 + col)     = ov0;
    *(s16x8*)(Hout + (size_t)n*1024 + col + 8) = ov1;
  }
}

// ---------------- layer 3: logits (H=6, C=10) ----------------
__global__ void k_al3(const ushort* __restrict__ G3, const float* __restrict__ a_s,
                      const float* __restrict__ a_d,
                      float* __restrict__ als, float* __restrict__ ald, int N){
  int n = blockIdx.x*256 + threadIdx.x;
  if (n >= N) return;
  const ushort* row = G3 + (size_t)n*60;
  #pragma unroll
  for (int h = 0; h < 6; ++h){
    float ps = 0.f, pd = 0.f;
    #pragma unroll
    for (int c = 0; c < 10; ++c){
      float v = bf2f(row[h*10 + c]);
      ps += v * a_s[h*10 + c];
      pd += v * a_d[h*10 + c];
    }
    als[(size_t)n*6 + h] = ps;
    ald[(size_t)n*6 + h] = pd;
  }
}

// ---------------- layer 3: edge-parallel online softmax + aggregate + mean ----------------
__global__ __launch_bounds__(64) void k_agg3(
    const ushort* __restrict__ G3,
    const ushort* __restrict__ Skip3,
    const float*  __restrict__ als,
    const float*  __restrict__ ald,
    const float*  __restrict__ b3,
    const float*  __restrict__ lb3,
    const int*    __restrict__ indptr,
    const int*    __restrict__ csrc,
    const float*  __restrict__ cew,
    float* __restrict__ out, int N)
{
  const int n = blockIdx.x;
  const int l = threadIdx.x;
  const int beg = indptr[n], deg = indptr[n+1] - beg;
  __shared__ float s_aldh[6];
  __shared__ int   s_src[64];
  __shared__ float s_wgt[64][6];
  __shared__ float s_o[6][10];
  if (l < 6) s_aldh[l] = ald[(size_t)n*6 + l];
  __syncthreads();
  float m0=-1e30f,m1=-1e30f,m2=-1e30f,m3=-1e30f,m4=-1e30f,m5=-1e30f;
  float d0=0.f,d1=0.f,d2=0.f,d3=0.f,d4=0.f,d5=0.f;
  for (int c0 = 0; c0 < deg; c0 += 64){
    int nc = min(64, deg - c0);
    bool act = l < nc;
    int s = act ? csrc[beg + c0 + l] : 0;
#define HP(hh, mm, dd) { \
    float e = -1e30f; \
    if (act){ float r_ = als[(size_t)s*6 + hh] + s_aldh[hh]; e = r_ > 0.f ? r_ : 0.2f*r_; } \
    float cm = e; \
    for (int o_ = 32; o_; o_ >>= 1) cm = fmaxf(cm, __shfl_xor(cm, o_)); \
    float nm = fmaxf(mm, cm); \
    float ex = act ? __expf(e - nm) : 0.f; \
    for (int o_ = 32; o_; o_ >>= 1) ex += __shfl_xor(ex, o_); \
    dd = dd * __expf(mm - nm) + ex; mm = nm; }
    HP(0,m0,d0) HP(1,m1,d1) HP(2,m2,d2) HP(3,m3,d3) HP(4,m4,d4) HP(5,m5,d5)
#undef HP
  }
  const int h = l / 10, c = l % 10;
  float o = 0.f;
  for (int c0 = 0; c0 < deg; c0 += 64){
    int nc = min(64, deg - c0);
    if (l < nc){
      int s = csrc[beg + c0 + l];
      s_src[l] = s;
      float w_ = cew[beg + c0 + l];
#define WP(hh, mm, dd) { \
      float r_ = als[(size_t)s*6 + hh] + s_aldh[hh]; \
      float e = r_ > 0.f ? r_ : 0.2f*r_; \
      s_wgt[l][hh] = __expf(e - mm) / (dd + 1e-16f) * w_; }
      WP(0,m0,d0) WP(1,m1,d1) WP(2,m2,d2) WP(3,m3,d3) WP(4,m4,d4) WP(5,m5,d5)
#undef WP
    }
    __syncthreads();
    if (l < 60){
      for (int i = 0; i < nc; ++i)
        o += s_wgt[i][h] * bf2f(G3[(size_t)s_src[i]*60 + l]);
    }
    __syncthreads();
  }
  if (l < 60) s_o[h][c] = o;
  __syncthreads();
  if (l < 10){
    float v = (s_o[0][l]+s_o[1][l]+s_o[2][l]+s_o[3][l]+s_o[4][l]+s_o[5][l]) * (1.0f/6.0f);
    v += b3[l] + lb3[l] + bf2f(Skip3[(size_t)n*10 + l]);
    out[(size_t)n*10 + l] = v;
  }
}

// ---------------- host ----------------
extern "C" void kernel_launch(void* const* d_in, const int* in_sizes, int n_in,
                              void* d_out, int out_size, void* d_ws, size_t ws_size,
                              hipStream_t stream)
{
  const int N = 20000, F = 128, E = 320000, ET = E + N;
  const int Mpad = 20224;            // 79*256 = 158*128
  const int F1 = 1024, NT = 2048;
  const int NWG1 = (Mpad/128)*(NT/128);   // 2528, %8==0
  const int NWG2 = (Mpad/256)*(NT/256);   // 632,  %8==0

  const float* x   = (const float*)d_in[0];
  const int*   ei  = (const int*)  d_in[1];
  const float* ew  = (const float*)d_in[2];
  const float* W1  = (const float*)d_in[3];
  const float* a1s = (const float*)d_in[4];
  const float* a1d = (const float*)d_in[5];
  const float* b1  = (const float*)d_in[6];
  const float* lw1 = (const float*)d_in[7];
  const float* lb1 = (const float*)d_in[8];
  const float* W2  = (const float*)d_in[9];
  const float* a2s = (const float*)d_in[10];
  const float* a2d = (const float*)d_in[11];
  const float* b2  = (const float*)d_in[12];
  const float* lw2 = (const float*)d_in[13];
  const float* lb2 = (const float*)d_in[14];
  const float* W3  = (const float*)d_in[15];
  const float* a3s = (const float*)d_in[16];
  const float* a3d = (const float*)d_in[17];
  const float* b3  = (const float*)d_in[18];
  const float* lw3 = (const float*)d_in[19];
  const float* lb3 = (const float*)d_in[20];

  char* ws = (char*)d_ws;
  size_t off = 0;
  auto alloc = [&](size_t bytes) -> void* {
    void* p = ws + off;
    off = (off + bytes + 255) & ~(size_t)255;
    return p;
  };
  ushort* Gatt = (ushort*)alloc((size_t)Mpad*F1*2);
  ushort* Skip = (ushort*)alloc((size_t)Mpad*F1*2);
  ushort* H    = (ushort*)alloc((size_t)Mpad*F1*2);
  ushort* xb   = (ushort*)alloc((size_t)Mpad*F*2);
  ushort* BT   = (ushort*)alloc((size_t)NT*1024*2);
  float*  als  = (float*) alloc((size_t)N*6*4);
  float*  ald  = (float*) alloc((size_t)N*6*4);
  int*    counts = (int*)alloc((size_t)2*N*4);
  int*    cursor = counts + N;
  int*    indptr = (int*)alloc((size_t)(N+1)*4);
  int*    csrc   = (int*)alloc((size_t)ET*4);
  float*  cew    = (float*)alloc((size_t)ET*4);
  if (off > ws_size) return;

  hipMemsetAsync(counts, 0, (size_t)2*N*4, stream);
  k_count<<<(ET+255)/256, 256, 0, stream>>>(ei, counts, E, ET);
  k_scan<<<1, 1024, 0, stream>>>(counts, indptr, N);
  k_fill<<<(ET+255)/256, 256, 0, stream>>>(ei, ew, indptr, cursor, csrc, cew, E, ET);
  k_f2b<<<(Mpad*F/8+255)/256, 256, 0, stream>>>(x, xb, N*F/8, Mpad*F/8);

  // ---- layer 1 (128^2 path) ----
  k_packB<<<dim3((F+31)/32, NT/32), 256, 0, stream>>>(W1, lw1, BT, F, 1024, 1024, NT);
  k_gemm<<<dim3(NWG1), 256, 0, stream>>>(xb, BT, Gatt, Skip, F, 1024, 1024, NT/128, NWG1/8);
  k_al<<<(N+3)/4, 256, 0, stream>>>(Gatt, a1s, a1d, als, ald, N);
  k_agg<<<Mpad, 256, 0, stream>>>(Gatt, Skip, als, ald, b1, lb1, indptr, csrc, cew, H, N);

  // ---- layer 2 (8-phase 256^2 path, v2) ----
  k_packB<<<dim3(F1/32, NT/32), 256, 0, stream>>>(W2, lw2, BT, F1, 1024, 1024, NT);
  k_gemm8<<<dim3(NWG2), 512, 0, stream>>>(H, BT, Gatt, Skip, F1, 1024, NWG2/8);
  k_al<<<(N+3)/4, 256, 0, stream>>>(Gatt, a2s, a2d, als, ald, N);
  k_agg<<<Mpad, 256, 0, stream>>>(Gatt, Skip, als, ald, b2, lb2, indptr, csrc, cew, H, N);

  // ---- layer 3 (128^2 path) ----
  k_packB<<<dim3(F1/32, 128/32), 256, 0, stream>>>(W3, lw3, BT, F1, 60, 10, 128);
  k_gemm<<<dim3(Mpad/128), 256, 0, stream>>>(H, BT, Gatt, Skip, F1, 60, 10, 1, 0);
  k_al3<<<(N+255)/256, 256, 0, stream>>>(Gatt, a3s, a3d, als, ald, N);
  k_agg3<<<N, 64, 0, stream>>>(Gatt, Skip, als, ald, b3, lb3, indptr, csrc, cew,
                               (float*)d_out, N);
}

// Round 8
// 502.316 us; speedup vs baseline: 1.0310x; 1.0031x over previous
//
#include <hip/hip_runtime.h>

typedef __attribute__((ext_vector_type(8))) short s16x8;
typedef __attribute__((ext_vector_type(8))) __bf16 bf16x8;
typedef __attribute__((ext_vector_type(4))) float f32x4;
typedef __attribute__((ext_vector_type(16))) float f32x16;

__device__ inline float bf2f(ushort u){ return __uint_as_float(((unsigned)u)<<16); }
__device__ inline ushort f2bf(float f){
  unsigned u = __float_as_uint(f);
  unsigned r = (u + 0x7fffu + ((u>>16)&1u)) >> 16;
  return (ushort)r;
}

__device__ inline void gl_lds16(const ushort* g, ushort* l){
  __builtin_amdgcn_global_load_lds(
      (const __attribute__((address_space(1))) unsigned int*)g,
      (__attribute__((address_space(3))) unsigned int*)l,
      16, 0, 0);
}

// ---------------- CSR build ----------------
__global__ void k_count(const int* __restrict__ ei, int* __restrict__ counts,
                        int E, int ET){
  int e = blockIdx.x*256 + threadIdx.x;
  if (e >= ET) return;
  int dst = (e < E) ? ei[E + e] : (e - E);
  atomicAdd(&counts[dst], 1);
}

__global__ __launch_bounds__(1024) void k_scan(const int* __restrict__ cnt,
                                               int* __restrict__ indptr, int N){
  __shared__ int part[1024];
  int t = threadIdx.x;
  int per = (N + 1023) / 1024;
  int base = t * per;
  int s = 0;
  for (int i = 0; i < per; ++i){ int idx = base + i; if (idx < N) s += cnt[idx]; }
  part[t] = s; __syncthreads();
  for (int off = 1; off < 1024; off <<= 1){
    int v = (t >= off) ? part[t-off] : 0;
    __syncthreads();
    if (t >= off) part[t] += v;
    __syncthreads();
  }
  int run = (t == 0) ? 0 : part[t-1];
  for (int i = 0; i < per; ++i){
    int idx = base + i;
    if (idx < N){ indptr[idx] = run; run += cnt[idx]; }
  }
  if (t == 1023) indptr[N] = run;
}

__global__ void k_fill(const int* __restrict__ ei, const float* __restrict__ ew,
                       const int* __restrict__ indptr, int* __restrict__ cursor,
                       int* __restrict__ csrc, float* __restrict__ cew,
                       int E, int ET){
  int e = blockIdx.x*256 + threadIdx.x;
  if (e >= ET) return;
  int src, dst; float w;
  if (e < E){ src = ei[e]; dst = ei[E + e]; w = ew[e]; }
  else { src = dst = e - E; w = 1.0f; }
  int pos = indptr[dst] + atomicAdd(&cursor[dst], 1);
  csrc[pos] = src; cew[pos] = w;
}

// ---------------- conversions / packing ----------------
__global__ void k_f2b(const float* __restrict__ x, ushort* __restrict__ xb,
                      int n8valid, int n8total){
  int i = blockIdx.x*256 + threadIdx.x;
  if (i >= n8total) return;
  s16x8 o = {0,0,0,0,0,0,0,0};
  if (i < n8valid){
    const float4* p = (const float4*)x + (size_t)i*2;
    float4 a = p[0], b = p[1];
    o[0]=(short)f2bf(a.x); o[1]=(short)f2bf(a.y); o[2]=(short)f2bf(a.z); o[3]=(short)f2bf(a.w);
    o[4]=(short)f2bf(b.x); o[5]=(short)f2bf(b.y); o[6]=(short)f2bf(b.z); o[7]=(short)f2bf(b.w);
  }
  *((s16x8*)xb + i) = o;
}

__global__ __launch_bounds__(256) void k_packB(
    const float* __restrict__ W, const float* __restrict__ LW,
    ushort* __restrict__ BT, int K, int NW, int NL, int Npad)
{
  __shared__ float tile[32][33];
  int k0 = blockIdx.x*32, n0 = blockIdx.y*32;
  int c = threadIdx.x & 31, r4 = threadIdx.x >> 5;
  #pragma unroll
  for (int rr = 0; rr < 32; rr += 8){
    int k = k0 + r4 + rr, n = n0 + c;
    float v = 0.f;
    if (k < K){
      if (n < NW)            v = W[(size_t)k*NW + n];
      else if (n < NW + NL)  v = LW[(size_t)k*NL + (n - NW)];
    }
    tile[r4+rr][c] = v;
  }
  __syncthreads();
  #pragma unroll
  for (int rr = 0; rr < 32; rr += 8){
    int n = n0 + r4 + rr, k = k0 + c;
    if (n < Npad && k < K) BT[(size_t)n*K + k] = f2bf(tile[c][r4+rr]);
  }
}

// ---------------- 128^2 MFMA GEMM (layers 1,3): proven R3 structure ----------------
__global__ __launch_bounds__(256) void k_gemm(
    const ushort* __restrict__ A, const ushort* __restrict__ BT,
    ushort* __restrict__ Gatt, ushort* __restrict__ Skip,
    int K, int GW, int SW, int NCB, int CPX)
{
  __shared__ ushort As[128*64];
  __shared__ ushort Bs[128*64];
  const int bid = blockIdx.x;
  const int lb = CPX ? ((bid & 7)*CPX + (bid >> 3)) : bid;
  const size_t row0 = (size_t)(lb / NCB) * 128;
  const size_t col0 = (size_t)(lb % NCB) * 128;
  const int t = threadIdx.x;
  const int l = t & 63, w = t >> 6;
  const int wr = w >> 1, wc = w & 1;
  const int sr = l >> 3;
  const int sk = ((l & 7) ^ sr) << 3;
  const ushort* gA = A  + (row0 + w*8 + sr)*(size_t)K + sk;
  const ushort* gB = BT + (col0 + w*8 + sr)*(size_t)K + sk;
  ushort* lA = As + w*512;
  ushort* lB = Bs + w*512;
  const int rf = l & 15;
  const int g4 = l >> 4;
  f32x4 acc[4][4] = {};

  for (int k0 = 0; k0 < K; k0 += 64){
    #pragma unroll
    for (int i = 0; i < 4; ++i){
      gl_lds16(gA + k0 + (size_t)(i*32)*K, lA + i*2048);
      gl_lds16(gB + k0 + (size_t)(i*32)*K, lB + i*2048);
    }
    __syncthreads();
    #pragma unroll
    for (int kk = 0; kk < 2; ++kk){
      const int koff = ((((kk<<2) | g4) ^ (rf & 7)) << 3);
      bf16x8 af[4], bfr[4];
      #pragma unroll
      for (int i = 0; i < 4; ++i)
        af[i] = __builtin_bit_cast(bf16x8, *(const s16x8*)(As + (wr*64 + i*16 + rf)*64 + koff));
      #pragma unroll
      for (int j = 0; j < 4; ++j)
        bfr[j] = __builtin_bit_cast(bf16x8, *(const s16x8*)(Bs + (wc*64 + j*16 + rf)*64 + koff));
      #pragma unroll
      for (int i = 0; i < 4; ++i)
        #pragma unroll
        for (int j = 0; j < 4; ++j)
          acc[i][j] = __builtin_amdgcn_mfma_f32_16x16x32_bf16(af[i], bfr[j], acc[i][j], 0, 0, 0);
    }
    __syncthreads();
  }

  #pragma unroll
  for (int i = 0; i < 4; ++i){
    #pragma unroll
    for (int j = 0; j < 4; ++j){
      int gc = (int)col0 + wc*64 + j*16 + rf;
      #pragma unroll
      for (int r = 0; r < 4; ++r){
        size_t gr = row0 + wr*64 + i*16 + (g4<<2) + r;
        float v = acc[i][j][r];
        if (gc < GW)            Gatt[gr*GW + gc] = f2bf(v);
        else if (gc < GW + SW)  Skip[gr*SW + (gc - GW)] = f2bf(v);
      }
    }
  }
}

// ---------------- 8-phase 256^2 MFMA GEMM v3 (layer 2): 32x32x16, 1 barrier/phase ----
#define STG8(p0, hh, ktv, offU) do { \
  const ushort* _g = (p0) + (((size_t)(hh))<<7)*(size_t)K + (((size_t)(ktv))<<6); \
  gl_lds16(_g, S + (offU) + (w<<9)); \
  gl_lds16(_g + ((size_t)K<<6), S + (offU) + 4096 + (w<<9)); \
} while(0)

#define RD_A32(base_) do { _Pragma("unroll") \
  for (int rt_ = 0; rt_ < 2; ++rt_){ \
    const ushort* rp_ = (base_) + (wr*64 + rt_*32 + l31)*64; \
    _Pragma("unroll") \
    for (int kk_ = 0; kk_ < 4; ++kk_) \
      av[rt_][kk_] = *(const bf16x8*)(rp_ + ((((kk_<<1) | g2) ^ sw_) << 3)); } \
} while(0)

#define RD_B32(base_, dst_) do { \
  const ushort* rp_ = (base_) + (wc*32 + l31)*64; \
  _Pragma("unroll") \
  for (int kk_ = 0; kk_ < 4; ++kk_) \
    dst_[kk_] = *(const bf16x8*)(rp_ + ((((kk_<<1) | g2) ^ sw_) << 3)); \
} while(0)

#define MM32(mh, nh, bv_) do { \
  __builtin_amdgcn_s_setprio(1); \
  _Pragma("unroll") \
  for (int kk_ = 0; kk_ < 4; ++kk_) \
    _Pragma("unroll") \
    for (int rt_ = 0; rt_ < 2; ++rt_) \
      acc[mh][nh][rt_] = __builtin_amdgcn_mfma_f32_32x32x16_bf16( \
          av[rt_][kk_], bv_[kk_], acc[mh][nh][rt_], 0, 0, 0); \
  __builtin_amdgcn_s_setprio(0); \
} while(0)

__global__ __launch_bounds__(512, 1) void k_gemm8(
    const ushort* __restrict__ A, const ushort* __restrict__ BT,
    ushort* __restrict__ Gatt, ushort* __restrict__ Skip,
    int K, int GW, int CPX)
{
  __shared__ ushort S[65536];                  // 128 KiB: 2 bufs x (A 32KB + B 32KB)
  const int bid = blockIdx.x;
  const int lb = (bid & 7)*CPX + (bid >> 3);   // XCD-chunked bijection (grid % 8 == 0)
  const size_t row0 = (size_t)(lb >> 3) * 256; // NCB = 8 col tiles
  const size_t col0 = (size_t)(lb & 7) * 256;
  const int t = threadIdx.x;
  const int l = t & 63, w = t >> 6;            // 8 waves
  const int wr = w >> 2, wc = w & 3;           // 2 x 4 wave grid; per-wave out 128x64
  const int l31 = l & 31, g2 = l >> 5;
  const int sw_ = l31 & 7;
  const int T = K >> 6;

  const int r0 = t >> 3, s0 = t & 7;
  const ushort* pA = A  + (row0 + r0)*(size_t)K + ((s0 ^ (r0 & 7)) << 3);
  const ushort* pB = BT + (col0 + r0)*(size_t)K + ((s0 ^ (r0 & 7)) << 3);

  f32x16 acc[2][2][2] = {};                    // [mh][nh][rowtile] 32x32 tiles
  bf16x8 av[2][4], bvlo[4], bvhi[4];

  // prologue: 4 halves of kt0 + A-lo/B-lo of kt1 (12 loads)
  STG8(pA, 0, 0, 0);
  STG8(pB, 0, 0, 16384);
  STG8(pA, 1, 0, 8192);
  STG8(pB, 1, 0, 24576);
  STG8(pA, 0, 1, 32768);
  STG8(pB, 0, 1, 49152);
  asm volatile("s_waitcnt vmcnt(4)");          // kt0's 4 halves complete; 2 in flight
  asm volatile("s_barrier" ::: "memory");

  for (int u = 0; u < T; ++u){
    const int b = u & 1;
    const int bbase = b << 15;
    const int nbase = bbase ^ 32768;
    const bool un1 = (u + 1 < T), un2 = (u + 2 < T);
    const ushort* Alo = S + bbase;
    const ushort* Ahi = S + bbase + 8192;
    const ushort* Blo = S + bbase + 16384;
    const ushort* Bhi = S + bbase + 24576;
    // p1: read A-lo + both B halves (bvhi latency hides under Q00); stage A-hi(u+1)
    RD_A32(Alo); RD_B32(Blo, bvlo); RD_B32(Bhi, bvhi);
    if (un1) STG8(pA, 1, u+1, nbase + 8192);
    MM32(0, 0, bvlo);
    asm volatile("s_barrier" ::: "memory");
    // p2: no reads; stage B-hi(u+1)
    if (un1) STG8(pB, 1, u+1, nbase + 24576);
    MM32(0, 1, bvhi);
    asm volatile("s_barrier" ::: "memory");
    // p3: read A-hi into av (dead after p2); stage A-lo(u+2)
    RD_A32(Ahi);
    if (un2) STG8(pA, 0, u+2, bbase);
    MM32(1, 0, bvlo);
    asm volatile("s_barrier" ::: "memory");
    // p4: no reads; stage B-lo(u+2); counted wait before barrier
    if (un2) STG8(pB, 0, u+2, bbase + 16384);
    MM32(1, 1, bvhi);
    if (un2) asm volatile("s_waitcnt vmcnt(4)");
    else     asm volatile("s_waitcnt vmcnt(0)");
    asm volatile("s_barrier" ::: "memory");
  }

  ushort* outp; int cb;
  if ((int)col0 < GW){ outp = Gatt; cb = (int)col0; }
  else               { outp = Skip; cb = (int)col0 - GW; }
  // C/D 32x32 layout: col = l&31, row = (r&3) + 8*(r>>2) + 4*g2
  #pragma unroll
  for (int mh = 0; mh < 2; ++mh)
    #pragma unroll
    for (int rt = 0; rt < 2; ++rt)
      #pragma unroll
      for (int r = 0; r < 16; ++r){
        size_t gr = row0 + mh*128 + wr*64 + rt*32 + (r&3) + ((r>>2)<<3) + (g2<<2);
        ushort* rp = outp + gr*1024 + cb;
        #pragma unroll
        for (int nh = 0; nh < 2; ++nh)
          rp[nh*128 + wc*32 + l31] = f2bf(acc[mh][nh][rt][r]);
      }
}

// ---------------- attention logits (layers 1-2: H=4, C=256) ----------------
__global__ __launch_bounds__(256) void k_al(const ushort* __restrict__ Gatt,
    const float* __restrict__ a_s, const float* __restrict__ a_d,
    float* __restrict__ als, float* __restrict__ ald, int N){
  int gw = (blockIdx.x*blockDim.x + threadIdx.x) >> 6;
  int l = threadIdx.x & 63;
  if (gw >= N) return;
  const ushort* row = Gatt + (size_t)gw*1024;
  int c0 = l*16;
  s16x8 v0 = *(const s16x8*)(row + c0);
  s16x8 v1 = *(const s16x8*)(row + c0 + 8);
  float ps = 0.f, pd = 0.f;
  #pragma unroll
  for (int q = 0; q < 8; ++q){
    float f0 = bf2f((ushort)v0[q]), f1 = bf2f((ushort)v1[q]);
    ps += f0*a_s[c0+q] + f1*a_s[c0+8+q];
    pd += f0*a_d[c0+q] + f1*a_d[c0+8+q];
  }
  #pragma unroll
  for (int off = 8; off; off >>= 1){
    ps += __shfl_down(ps, off);
    pd += __shfl_down(pd, off);
  }
  if ((l & 15) == 0){
    als[(size_t)gw*4 + (l>>4)] = ps;
    ald[(size_t)gw*4 + (l>>4)] = pd;
  }
}

// ---------------- softmax + aggregate + bias + skip + ELU (layers 1-2) ----------------
__global__ __launch_bounds__(256) void k_agg(
    const ushort* __restrict__ Gatt,
    const ushort* __restrict__ Skip,
    const float*  __restrict__ als,
    const float*  __restrict__ ald,
    const float*  __restrict__ bias,
    const float*  __restrict__ lbias,
    const int*    __restrict__ indptr,
    const int*    __restrict__ csrc,
    const float*  __restrict__ cew,
    ushort* __restrict__ Hout,
    int N)
{
  const int n = blockIdx.x;
  const int t = threadIdx.x;
  if (n >= N){
    ushort4 z = {0,0,0,0};
    *(ushort4*)(Hout + (size_t)n*1024 + t*4) = z;
    return;
  }
  const int l = t & 63, w = t >> 6;
  const int beg = indptr[n];
  const int deg = indptr[n+1] - beg;
  __shared__ float s_ald[4], s_m[4], s_den[4];
  __shared__ int   s_src[64];
  __shared__ float s_w[64][4];
  __shared__ float s_part[3][64][16];
  if (t < 4) s_ald[t] = ald[(size_t)n*4 + t];
  __syncthreads();
  const bool fast = (deg <= 64);

  if (fast){
    int e2 = t >> 2, hh = t & 3;
    if (e2 < deg){
      int s = csrc[beg + e2];
      if (hh == 0) s_src[e2] = s;
      float r_ = als[(size_t)s*4 + hh] + s_ald[hh];
      s_w[e2][hh] = r_ > 0.f ? r_ : 0.2f*r_;
    }
    __syncthreads();
    float mye = (l < deg) ? s_w[l][w] : -1e30f;
    float mx = mye;
    #pragma unroll
    for (int o = 32; o; o >>= 1) mx = fmaxf(mx, __shfl_xor(mx, o));
    float ex = (l < deg) ? __expf(mye - mx) : 0.f;
    float den = ex;
    #pragma unroll
    for (int o = 32; o; o >>= 1) den += __shfl_xor(den, o);
    den += 1e-16f;
    if (l < deg) s_w[l][w] = ex / den * cew[beg + l];
    __syncthreads();
  } else {
    const float aldh = s_ald[w];
    float mx = -1e30f;
    for (int i = l; i < deg; i += 64){
      int s = csrc[beg+i];
      float e = als[(size_t)s*4 + w] + aldh;
      e = e > 0.f ? e : 0.2f*e;
      mx = fmaxf(mx, e);
    }
    #pragma unroll
    for (int off = 32; off; off >>= 1) mx = fmaxf(mx, __shfl_xor(mx, off));
    if (l == 0) s_m[w] = mx;
    __syncthreads();
    const float mh = s_m[w];
    float den = 0.f;
    for (int i = l; i < deg; i += 64){
      int s = csrc[beg+i];
      float e = als[(size_t)s*4 + w] + aldh;
      e = e > 0.f ? e : 0.2f*e;
      den += __expf(e - mh);
    }
    #pragma unroll
    for (int off = 32; off; off >>= 1) den += __shfl_xor(den, off);
    if (l == 0) s_den[w] = den + 1e-16f;
    __syncthreads();
  }

  const int h2 = l >> 4;
  const ushort* gbase = Gatt + (size_t)l*16;
  float a[16];
  #pragma unroll
  for (int q = 0; q < 16; ++q) a[q] = 0.f;
  for (int c0 = 0; c0 < deg; c0 += 64){
    int nc = min(64, deg - c0);
    if (!fast){
      int ei2 = t >> 2, hh = t & 3;
      if (ei2 < nc){
        int s = csrc[beg + c0 + ei2];
        if (hh == 0) s_src[ei2] = s;
        float e = als[(size_t)s*4 + hh] + s_ald[hh];
        e = e > 0.f ? e : 0.2f*e;
        s_w[ei2][hh] = __expf(e - s_m[hh]) / s_den[hh] * cew[beg + c0 + ei2];
      }
      __syncthreads();
    }
    for (int j = w; j < nc; j += 4){
      int s = s_src[j];
      float wg = s_w[j][h2];
      const ushort* rp = gbase + (size_t)s*1024;
      s16x8 h0 = *(const s16x8*)rp;
      s16x8 h1 = *(const s16x8*)(rp + 8);
      #pragma unroll
      for (int q = 0; q < 8; ++q) a[q] += wg * bf2f((ushort)h0[q]);
      #pragma unroll
      for (int q = 0; q < 8; ++q) a[q+8] += wg * bf2f((ushort)h1[q]);
    }
    __syncthreads();
  }
  if (w){
    #pragma unroll
    for (int q = 0; q < 16; ++q) s_part[w-1][l][q] = a[q];
  }
  __syncthreads();
  if (w == 0){
    #pragma unroll
    for (int q = 0; q < 16; ++q) a[q] += s_part[0][l][q] + s_part[1][l][q] + s_part[2][l][q];
    const int col = l*16;
    s16x8 sk0 = *(const s16x8*)(Skip + (size_t)n*1024 + col);
    s16x8 sk1 = *(const s16x8*)(Skip + (size_t)n*1024 + col + 8);
    s16x8 ov0, ov1;
    #pragma unroll
    for (int q = 0; q < 8; ++q){
      float v = a[q] + bias[col+q] + lbias[col+q] + bf2f((ushort)sk0[q]);
      v = v > 0.f ? v : __expf(v) - 1.f;
      ov0[q] = (short)f2bf(v);
      float v2 = a[q+8] + bias[col+8+q] + lbias[col+8+q] + bf2f((ushort)sk1[q]);
      v2 = v2 > 0.f ? v2 : __expf(v2) - 1.f;
      ov1[q] = (short)f2bf(v2);
    }
    *(s16x8*)(Hout + (size_t)n*1024 + col)     = ov0;
    *(s16x8*)(Hout + (size_t)n*1024 + col + 8) = ov1;
  }
}

// ---------------- layer 3: logits (H=6, C=10) ----------------
__global__ void k_al3(const ushort* __restrict__ G3, const float* __restrict__ a_s,
                      const float* __restrict__ a_d,
                      float* __restrict__ als, float* __restrict__ ald, int N){
  int n = blockIdx.x*256 + threadIdx.x;
  if (n >= N) return;
  const ushort* row = G3 + (size_t)n*60;
  #pragma unroll
  for (int h = 0; h < 6; ++h){
    float ps = 0.f, pd = 0.f;
    #pragma unroll
    for (int c = 0; c < 10; ++c){
      float v = bf2f(row[h*10 + c]);
      ps += v * a_s[h*10 + c];
      pd += v * a_d[h*10 + c];
    }
    als[(size_t)n*6 + h] = ps;
    ald[(size_t)n*6 + h] = pd;
  }
}

// ---------------- layer 3: edge-parallel online softmax + aggregate + mean ----------------
__global__ __launch_bounds__(64) void k_agg3(
    const ushort* __restrict__ G3,
    const ushort* __restrict__ Skip3,
    const float*  __restrict__ als,
    const float*  __restrict__ ald,
    const float*  __restrict__ b3,
    const float*  __restrict__ lb3,
    const int*    __restrict__ indptr,
    const int*    __restrict__ csrc,
    const float*  __restrict__ cew,
    float* __restrict__ out, int N)
{
  const int n = blockIdx.x;
  const int l = threadIdx.x;
  const int beg = indptr[n], deg = indptr[n+1] - beg;
  __shared__ float s_aldh[6];
  __shared__ int   s_src[64];
  __shared__ float s_wgt[64][6];
  __shared__ float s_o[6][10];
  if (l < 6) s_aldh[l] = ald[(size_t)n*6 + l];
  __syncthreads();
  float m0=-1e30f,m1=-1e30f,m2=-1e30f,m3=-1e30f,m4=-1e30f,m5=-1e30f;
  float d0=0.f,d1=0.f,d2=0.f,d3=0.f,d4=0.f,d5=0.f;
  for (int c0 = 0; c0 < deg; c0 += 64){
    int nc = min(64, deg - c0);
    bool act = l < nc;
    int s = act ? csrc[beg + c0 + l] : 0;
#define HP(hh, mm, dd) { \
    float e = -1e30f; \
    if (act){ float r_ = als[(size_t)s*6 + hh] + s_aldh[hh]; e = r_ > 0.f ? r_ : 0.2f*r_; } \
    float cm = e; \
    for (int o_ = 32; o_; o_ >>= 1) cm = fmaxf(cm, __shfl_xor(cm, o_)); \
    float nm = fmaxf(mm, cm); \
    float ex = act ? __expf(e - nm) : 0.f; \
    for (int o_ = 32; o_; o_ >>= 1) ex += __shfl_xor(ex, o_); \
    dd = dd * __expf(mm - nm) + ex; mm = nm; }
    HP(0,m0,d0) HP(1,m1,d1) HP(2,m2,d2) HP(3,m3,d3) HP(4,m4,d4) HP(5,m5,d5)
#undef HP
  }
  const int h = l / 10, c = l % 10;
  float o = 0.f;
  for (int c0 = 0; c0 < deg; c0 += 64){
    int nc = min(64, deg - c0);
    if (l < nc){
      int s = csrc[beg + c0 + l];
      s_src[l] = s;
      float w_ = cew[beg + c0 + l];
#define WP(hh, mm, dd) { \
      float r_ = als[(size_t)s*6 + hh] + s_aldh[hh]; \
      float e = r_ > 0.f ? r_ : 0.2f*r_; \
      s_wgt[l][hh] = __expf(e - mm) / (dd + 1e-16f) * w_; }
      WP(0,m0,d0) WP(1,m1,d1) WP(2,m2,d2) WP(3,m3,d3) WP(4,m4,d4) WP(5,m5,d5)
#undef WP
    }
    __syncthreads();
    if (l < 60){
      for (int i = 0; i < nc; ++i)
        o += s_wgt[i][h] * bf2f(G3[(size_t)s_src[i]*60 + l]);
    }
    __syncthreads();
  }
  if (l < 60) s_o[h][c] = o;
  __syncthreads();
  if (l < 10){
    float v = (s_o[0][l]+s_o[1][l]+s_o[2][l]+s_o[3][l]+s_o[4][l]+s_o[5][l]) * (1.0f/6.0f);
    v += b3[l] + lb3[l] + bf2f(Skip3[(size_t)n*10 + l]);
    out[(size_t)n*10 + l] = v;
  }
}

// ---------------- host ----------------
extern "C" void kernel_launch(void* const* d_in, const int* in_sizes, int n_in,
                              void* d_out, int out_size, void* d_ws, size_t ws_size,
                              hipStream_t stream)
{
  const int N = 20000, F = 128, E = 320000, ET = E + N;
  const int Mpad = 20224;            // 79*256 = 158*128
  const int F1 = 1024, NT = 2048;
  const int NWG1 = (Mpad/128)*(NT/128);   // 2528, %8==0
  const int NWG2 = (Mpad/256)*(NT/256);   // 632,  %8==0

  const float* x   = (const float*)d_in[0];
  const int*   ei  = (const int*)  d_in[1];
  const float* ew  = (const float*)d_in[2];
  const float* W1  = (const float*)d_in[3];
  const float* a1s = (const float*)d_in[4];
  const float* a1d = (const float*)d_in[5];
  const float* b1  = (const float*)d_in[6];
  const float* lw1 = (const float*)d_in[7];
  const float* lb1 = (const float*)d_in[8];
  const float* W2  = (const float*)d_in[9];
  const float* a2s = (const float*)d_in[10];
  const float* a2d = (const float*)d_in[11];
  const float* b2  = (const float*)d_in[12];
  const float* lw2 = (const float*)d_in[13];
  const float* lb2 = (const float*)d_in[14];
  const float* W3  = (const float*)d_in[15];
  const float* a3s = (const float*)d_in[16];
  const float* a3d = (const float*)d_in[17];
  const float* b3  = (const float*)d_in[18];
  const float* lw3 = (const float*)d_in[19];
  const float* lb3 = (const float*)d_in[20];

  char* ws = (char*)d_ws;
  size_t off = 0;
  auto alloc = [&](size_t bytes) -> void* {
    void* p = ws + off;
    off = (off + bytes + 255) & ~(size_t)255;
    return p;
  };
  ushort* Gatt = (ushort*)alloc((size_t)Mpad*F1*2);
  ushort* Skip = (ushort*)alloc((size_t)Mpad*F1*2);
  ushort* H    = (ushort*)alloc((size_t)Mpad*F1*2);
  ushort* xb   = (ushort*)alloc((size_t)Mpad*F*2);
  ushort* BT   = (ushort*)alloc((size_t)NT*1024*2);
  float*  als  = (float*) alloc((size_t)N*6*4);
  float*  ald  = (float*) alloc((size_t)N*6*4);
  int*    counts = (int*)alloc((size_t)2*N*4);
  int*    cursor = counts + N;
  int*    indptr = (int*)alloc((size_t)(N+1)*4);
  int*    csrc   = (int*)alloc((size_t)ET*4);
  float*  cew    = (float*)alloc((size_t)ET*4);
  if (off > ws_size) return;

  hipMemsetAsync(counts, 0, (size_t)2*N*4, stream);
  k_count<<<(ET+255)/256, 256, 0, stream>>>(ei, counts, E, ET);
  k_scan<<<1, 1024, 0, stream>>>(counts, indptr, N);
  k_fill<<<(ET+255)/256, 256, 0, stream>>>(ei, ew, indptr, cursor, csrc, cew, E, ET);
  k_f2b<<<(Mpad*F/8+255)/256, 256, 0, stream>>>(x, xb, N*F/8, Mpad*F/8);

  // ---- layer 1 (128^2 path) ----
  k_packB<<<dim3((F+31)/32, NT/32), 256, 0, stream>>>(W1, lw1, BT, F, 1024, 1024, NT);
  k_gemm<<<dim3(NWG1), 256, 0, stream>>>(xb, BT, Gatt, Skip, F, 1024, 1024, NT/128, NWG1/8);
  k_al<<<(N+3)/4, 256, 0, stream>>>(Gatt, a1s, a1d, als, ald, N);
  k_agg<<<Mpad, 256, 0, stream>>>(Gatt, Skip, als, ald, b1, lb1, indptr, csrc, cew, H, N);

  // ---- layer 2 (8-phase 256^2 path, v3: 32x32x16) ----
  k_packB<<<dim3(F1/32, NT/32), 256, 0, stream>>>(W2, lw2, BT, F1, 1024, 1024, NT);
  k_gemm8<<<dim3(NWG2), 512, 0, stream>>>(H, BT, Gatt, Skip, F1, 1024, NWG2/8);
  k_al<<<(N+3)/4, 256, 0, stream>>>(Gatt, a2s, a2d, als, ald, N);
  k_agg<<<Mpad, 256, 0, stream>>>(Gatt, Skip, als, ald, b2, lb2, indptr, csrc, cew, H, N);

  // ---- layer 3 (128^2 path) ----
  k_packB<<<dim3(F1/32, 128/32), 256, 0, stream>>>(W3, lw3, BT, F1, 60, 10, 128);
  k_gemm<<<dim3(Mpad/128), 256, 0, stream>>>(H, BT, Gatt, Skip, F1, 60, 10, 1, 0);
  k_al3<<<(N+255)/256, 256, 0, stream>>>(Gatt, a3s, a3d, als, ald, N);
  k_agg3<<<N, 64, 0, stream>>>(Gatt, Skip, als, ald, b3, lb3, indptr, csrc, cew,
                               (float*)d_out, N);
}

// Round 9
// 501.646 us; speedup vs baseline: 1.0324x; 1.0013x over previous
//
#include <hip/hip_runtime.h>

typedef __attribute__((ext_vector_type(8))) short s16x8;
typedef __attribute__((ext_vector_type(8))) __bf16 bf16x8;
typedef __attribute__((ext_vector_type(4))) float f32x4;

__device__ inline float bf2f(ushort u){ return __uint_as_float(((unsigned)u)<<16); }
__device__ inline ushort f2bf(float f){
  unsigned u = __float_as_uint(f);
  unsigned r = (u + 0x7fffu + ((u>>16)&1u)) >> 16;
  return (ushort)r;
}

__device__ inline void gl_lds16(const ushort* g, ushort* l){
  __builtin_amdgcn_global_load_lds(
      (const __attribute__((address_space(1))) unsigned int*)g,
      (__attribute__((address_space(3))) unsigned int*)l,
      16, 0, 0);
}

// ---------------- CSR build ----------------
__global__ void k_count(const int* __restrict__ ei, int* __restrict__ counts,
                        int E, int ET){
  int e = blockIdx.x*256 + threadIdx.x;
  if (e >= ET) return;
  int dst = (e < E) ? ei[E + e] : (e - E);
  atomicAdd(&counts[dst], 1);
}

__global__ __launch_bounds__(1024) void k_scan(const int* __restrict__ cnt,
                                               int* __restrict__ indptr, int N){
  __shared__ int part[1024];
  int t = threadIdx.x;
  int per = (N + 1023) / 1024;
  int base = t * per;
  int s = 0;
  for (int i = 0; i < per; ++i){ int idx = base + i; if (idx < N) s += cnt[idx]; }
  part[t] = s; __syncthreads();
  for (int off = 1; off < 1024; off <<= 1){
    int v = (t >= off) ? part[t-off] : 0;
    __syncthreads();
    if (t >= off) part[t] += v;
    __syncthreads();
  }
  int run = (t == 0) ? 0 : part[t-1];
  for (int i = 0; i < per; ++i){
    int idx = base + i;
    if (idx < N){ indptr[idx] = run; run += cnt[idx]; }
  }
  if (t == 1023) indptr[N] = run;
}

__global__ void k_fill(const int* __restrict__ ei, const float* __restrict__ ew,
                       const int* __restrict__ indptr, int* __restrict__ cursor,
                       int* __restrict__ csrc, float* __restrict__ cew,
                       int E, int ET){
  int e = blockIdx.x*256 + threadIdx.x;
  if (e >= ET) return;
  int src, dst; float w;
  if (e < E){ src = ei[e]; dst = ei[E + e]; w = ew[e]; }
  else { src = dst = e - E; w = 1.0f; }
  int pos = indptr[dst] + atomicAdd(&cursor[dst], 1);
  csrc[pos] = src; cew[pos] = w;
}

// ---------------- conversions / packing ----------------
__global__ void k_f2b(const float* __restrict__ x, ushort* __restrict__ xb,
                      int n8valid, int n8total){
  int i = blockIdx.x*256 + threadIdx.x;
  if (i >= n8total) return;
  s16x8 o = {0,0,0,0,0,0,0,0};
  if (i < n8valid){
    const float4* p = (const float4*)x + (size_t)i*2;
    float4 a = p[0], b = p[1];
    o[0]=(short)f2bf(a.x); o[1]=(short)f2bf(a.y); o[2]=(short)f2bf(a.z); o[3]=(short)f2bf(a.w);
    o[4]=(short)f2bf(b.x); o[5]=(short)f2bf(b.y); o[6]=(short)f2bf(b.z); o[7]=(short)f2bf(b.w);
  }
  *((s16x8*)xb + i) = o;
}

__global__ __launch_bounds__(256) void k_packB(
    const float* __restrict__ W, const float* __restrict__ LW,
    ushort* __restrict__ BT, int K, int NW, int NL, int Npad)
{
  __shared__ float tile[32][33];
  int k0 = blockIdx.x*32, n0 = blockIdx.y*32;
  int c = threadIdx.x & 31, r4 = threadIdx.x >> 5;
  #pragma unroll
  for (int rr = 0; rr < 32; rr += 8){
    int k = k0 + r4 + rr, n = n0 + c;
    float v = 0.f;
    if (k < K){
      if (n < NW)            v = W[(size_t)k*NW + n];
      else if (n < NW + NL)  v = LW[(size_t)k*NL + (n - NW)];
    }
    tile[r4+rr][c] = v;
  }
  __syncthreads();
  #pragma unroll
  for (int rr = 0; rr < 32; rr += 8){
    int n = n0 + r4 + rr, k = k0 + c;
    if (n < Npad && k < K) BT[(size_t)n*K + k] = f2bf(tile[c][r4+rr]);
  }
}

// ---------------- 128^2 MFMA GEMM (layers 1,3): proven R3 structure ----------------
__global__ __launch_bounds__(256) void k_gemm(
    const ushort* __restrict__ A, const ushort* __restrict__ BT,
    ushort* __restrict__ Gatt, ushort* __restrict__ Skip,
    int K, int GW, int SW, int NCB, int CPX)
{
  __shared__ ushort As[128*64];
  __shared__ ushort Bs[128*64];
  const int bid = blockIdx.x;
  const int lb = CPX ? ((bid & 7)*CPX + (bid >> 3)) : bid;
  const size_t row0 = (size_t)(lb / NCB) * 128;
  const size_t col0 = (size_t)(lb % NCB) * 128;
  const int t = threadIdx.x;
  const int l = t & 63, w = t >> 6;
  const int wr = w >> 1, wc = w & 1;
  const int sr = l >> 3;
  const int sk = ((l & 7) ^ sr) << 3;
  const ushort* gA = A  + (row0 + w*8 + sr)*(size_t)K + sk;
  const ushort* gB = BT + (col0 + w*8 + sr)*(size_t)K + sk;
  ushort* lA = As + w*512;
  ushort* lB = Bs + w*512;
  const int rf = l & 15;
  const int g4 = l >> 4;
  f32x4 acc[4][4] = {};

  for (int k0 = 0; k0 < K; k0 += 64){
    #pragma unroll
    for (int i = 0; i < 4; ++i){
      gl_lds16(gA + k0 + (size_t)(i*32)*K, lA + i*2048);
      gl_lds16(gB + k0 + (size_t)(i*32)*K, lB + i*2048);
    }
    __syncthreads();
    #pragma unroll
    for (int kk = 0; kk < 2; ++kk){
      const int koff = ((((kk<<2) | g4) ^ (rf & 7)) << 3);
      bf16x8 af[4], bfr[4];
      #pragma unroll
      for (int i = 0; i < 4; ++i)
        af[i] = __builtin_bit_cast(bf16x8, *(const s16x8*)(As + (wr*64 + i*16 + rf)*64 + koff));
      #pragma unroll
      for (int j = 0; j < 4; ++j)
        bfr[j] = __builtin_bit_cast(bf16x8, *(const s16x8*)(Bs + (wc*64 + j*16 + rf)*64 + koff));
      #pragma unroll
      for (int i = 0; i < 4; ++i)
        #pragma unroll
        for (int j = 0; j < 4; ++j)
          acc[i][j] = __builtin_amdgcn_mfma_f32_16x16x32_bf16(af[i], bfr[j], acc[i][j], 0, 0, 0);
    }
    __syncthreads();
  }

  #pragma unroll
  for (int i = 0; i < 4; ++i){
    #pragma unroll
    for (int j = 0; j < 4; ++j){
      int gc = (int)col0 + wc*64 + j*16 + rf;
      #pragma unroll
      for (int r = 0; r < 4; ++r){
        size_t gr = row0 + wr*64 + i*16 + (g4<<2) + r;
        float v = acc[i][j][r];
        if (gc < GW)            Gatt[gr*GW + gc] = f2bf(v);
        else if (gc < GW + SW)  Skip[gr*SW + (gc - GW)] = f2bf(v);
      }
    }
  }
}

// ---------------- 8-phase 256^2 MFMA GEMM v4 (layer 2) ----------------
// R8 sync skeleton (1 barrier/phase, counted vmcnt(4)) + R7 conflict-free 16x16
// read macros. Reads: p1 A-lo+B-lo (12), p2 B-hi (4), p3 A-hi (8), p4 none.
#define STG8(p0, hh, ktv, offU) do { \
  const ushort* _g = (p0) + (((size_t)(hh))<<7)*(size_t)K + (((size_t)(ktv))<<6); \
  gl_lds16(_g, S + (offU) + (w<<9)); \
  gl_lds16(_g + ((size_t)K<<6), S + (offU) + 4096 + (w<<9)); \
} while(0)

#define RD_A(base_) do { _Pragma("unroll") \
  for (int i_ = 0; i_ < 4; ++i_){ \
    const int hr = wr*64 + i_*16 + rf; const int sw = hr & 7; \
    av[i_][0] = *(const bf16x8*)((base_) + hr*64 + ((g4 ^ sw) << 3)); \
    av[i_][1] = *(const bf16x8*)((base_) + hr*64 + (((4|g4) ^ sw) << 3)); } \
} while(0)

#define RD_B(base_, dst_) do { _Pragma("unroll") \
  for (int j_ = 0; j_ < 2; ++j_){ \
    const int cf = wc*32 + j_*16 + rf; const int sw = cf & 7; \
    dst_[j_][0] = *(const bf16x8*)((base_) + cf*64 + ((g4 ^ sw) << 3)); \
    dst_[j_][1] = *(const bf16x8*)((base_) + cf*64 + (((4|g4) ^ sw) << 3)); } \
} while(0)

#define MM8(mh, nh, bv_) do { \
  __builtin_amdgcn_s_setprio(1); \
  _Pragma("unroll") \
  for (int kk_ = 0; kk_ < 2; ++kk_) \
    _Pragma("unroll") \
    for (int i_ = 0; i_ < 4; ++i_) \
      _Pragma("unroll") \
      for (int j_ = 0; j_ < 2; ++j_) \
        acc[mh][nh][i_][j_] = __builtin_amdgcn_mfma_f32_16x16x32_bf16( \
            av[i_][kk_], bv_[j_][kk_], acc[mh][nh][i_][j_], 0, 0, 0); \
  __builtin_amdgcn_s_setprio(0); \
} while(0)

__global__ __launch_bounds__(512, 1) void k_gemm8(
    const ushort* __restrict__ A, const ushort* __restrict__ BT,
    ushort* __restrict__ Gatt, ushort* __restrict__ Skip,
    int K, int GW, int CPX)
{
  __shared__ ushort S[65536];                  // 128 KiB: 2 bufs x (A 32KB + B 32KB)
  const int bid = blockIdx.x;
  const int lb = (bid & 7)*CPX + (bid >> 3);   // XCD-chunked bijection (grid % 8 == 0)
  const size_t row0 = (size_t)(lb >> 3) * 256; // NCB = 8 col tiles
  const size_t col0 = (size_t)(lb & 7) * 256;
  const int t = threadIdx.x;
  const int l = t & 63, w = t >> 6;            // 8 waves
  const int wr = w >> 2, wc = w & 3;           // 2 x 4 wave grid
  const int rf = l & 15, g4 = l >> 4;
  const int T = K >> 6;

  const int r0 = t >> 3, s0 = t & 7;
  const ushort* pA = A  + (row0 + r0)*(size_t)K + ((s0 ^ (r0 & 7)) << 3);
  const ushort* pB = BT + (col0 + r0)*(size_t)K + ((s0 ^ (r0 & 7)) << 3);

  f32x4 acc[2][2][4][2] = {};
  bf16x8 av[4][2], bvlo[2][2], bvhi[2][2];

  // prologue: 4 halves of kt0 + A-lo/B-lo of kt1 (12 loads)
  STG8(pA, 0, 0, 0);
  STG8(pB, 0, 0, 16384);
  STG8(pA, 1, 0, 8192);
  STG8(pB, 1, 0, 24576);
  STG8(pA, 0, 1, 32768);
  STG8(pB, 0, 1, 49152);
  asm volatile("s_waitcnt vmcnt(4)");          // kt0's 4 halves complete; 2 in flight
  asm volatile("s_barrier" ::: "memory");

  for (int u = 0; u < T; ++u){
    const int b = u & 1;
    const int bbase = b << 15;
    const int nbase = bbase ^ 32768;
    const bool un1 = (u + 1 < T), un2 = (u + 2 < T);
    const ushort* Alo = S + bbase;
    const ushort* Ahi = S + bbase + 8192;
    const ushort* Blo = S + bbase + 16384;
    const ushort* Bhi = S + bbase + 24576;
    // p1: Q00 — read A-lo + B-lo; stage A-hi(u+1)
    RD_A(Alo); RD_B(Blo, bvlo);
    if (un1) STG8(pA, 1, u+1, nbase + 8192);
    MM8(0, 0, bvlo);
    asm volatile("s_barrier" ::: "memory");
    // p2: Q01 — read B-hi (A kept); stage B-hi(u+1)
    RD_B(Bhi, bvhi);
    if (un1) STG8(pB, 1, u+1, nbase + 24576);
    MM8(0, 1, bvhi);
    asm volatile("s_barrier" ::: "memory");
    // p3: Q11 — read A-hi (B-hi kept); stage A-lo(u+2) (A-lo last read p1)
    RD_A(Ahi);
    if (un2) STG8(pA, 0, u+2, bbase);
    MM8(1, 1, bvhi);
    asm volatile("s_barrier" ::: "memory");
    // p4: Q10 — no reads (A-hi + B-lo kept); stage B-lo(u+2); counted wait
    if (un2) STG8(pB, 0, u+2, bbase + 16384);
    MM8(1, 0, bvlo);
    if (un2) asm volatile("s_waitcnt vmcnt(4)");
    else     asm volatile("s_waitcnt vmcnt(0)");
    asm volatile("s_barrier" ::: "memory");
  }

  ushort* outp; int cb;
  if ((int)col0 < GW){ outp = Gatt; cb = (int)col0; }
  else               { outp = Skip; cb = (int)col0 - GW; }
  #pragma unroll
  for (int mh = 0; mh < 2; ++mh)
    #pragma unroll
    for (int i = 0; i < 4; ++i)
      #pragma unroll
      for (int rr = 0; rr < 4; ++rr){
        size_t gr = row0 + mh*128 + wr*64 + i*16 + (g4<<2) + rr;
        ushort* rp = outp + gr*1024 + cb;
        #pragma unroll
        for (int nh = 0; nh < 2; ++nh)
          #pragma unroll
          for (int j = 0; j < 2; ++j)
            rp[nh*128 + wc*32 + j*16 + rf] = f2bf(acc[mh][nh][i][j][rr]);
      }
}

// ---------------- attention logits (layers 1-2: H=4, C=256) ----------------
__global__ __launch_bounds__(256) void k_al(const ushort* __restrict__ Gatt,
    const float* __restrict__ a_s, const float* __restrict__ a_d,
    float* __restrict__ als, float* __restrict__ ald, int N){
  int gw = (blockIdx.x*blockDim.x + threadIdx.x) >> 6;
  int l = threadIdx.x & 63;
  if (gw >= N) return;
  const ushort* row = Gatt + (size_t)gw*1024;
  int c0 = l*16;
  s16x8 v0 = *(const s16x8*)(row + c0);
  s16x8 v1 = *(const s16x8*)(row + c0 + 8);
  float ps = 0.f, pd = 0.f;
  #pragma unroll
  for (int q = 0; q < 8; ++q){
    float f0 = bf2f((ushort)v0[q]), f1 = bf2f((ushort)v1[q]);
    ps += f0*a_s[c0+q] + f1*a_s[c0+8+q];
    pd += f0*a_d[c0+q] + f1*a_d[c0+8+q];
  }
  #pragma unroll
  for (int off = 8; off; off >>= 1){
    ps += __shfl_down(ps, off);
    pd += __shfl_down(pd, off);
  }
  if ((l & 15) == 0){
    als[(size_t)gw*4 + (l>>4)] = ps;
    ald[(size_t)gw*4 + (l>>4)] = pd;
  }
}

// ---------------- softmax + aggregate + bias + skip + ELU: wave-per-node ----------------
// One wave per node (4 nodes/block), no barriers. Lane role in weight phases:
// edge = chunk + (l>>2), head = l&3. Gather: all 64 lanes read one 2KB row.
__global__ __launch_bounds__(256) void k_agg(
    const ushort* __restrict__ Gatt,   // [Mpad][1024] bf16
    const ushort* __restrict__ Skip,   // [Mpad][1024] bf16
    const float*  __restrict__ als,    // [N][4]
    const float*  __restrict__ ald,    // [N][4]
    const float*  __restrict__ bias,   // [1024]
    const float*  __restrict__ lbias,  // [1024]
    const int*    __restrict__ indptr,
    const int*    __restrict__ csrc,
    const float*  __restrict__ cew,
    ushort* __restrict__ Hout,         // [Mpad][1024] bf16
    int N)
{
  const int t = threadIdx.x;
  const int l = t & 63, w = t >> 6;
  const int n = blockIdx.x*4 + w;
  const int h2 = l >> 4;               // head of cols l*16..l*16+15
  const int col = l*16;
  if (n >= N){
    s16x8 z = {0,0,0,0,0,0,0,0};
    *(s16x8*)(Hout + (size_t)n*1024 + col)     = z;
    *(s16x8*)(Hout + (size_t)n*1024 + col + 8) = z;
    return;
  }
  const int beg = indptr[n];
  const int deg = indptr[n+1] - beg;
  const int hh = l & 3;
  const float aldh = ald[(size_t)n*4 + hh];

  // pass 1: online per-head max / denominator (lane tracks head hh)
  float m = -1e30f, d = 0.f;
  for (int c0 = 0; c0 < deg; c0 += 16){
    int i = c0 + (l >> 2);
    bool act = (i < deg);
    float e = -1e30f;
    if (act){
      int s = csrc[beg + i];
      float r_ = als[(size_t)s*4 + hh] + aldh;
      e = r_ > 0.f ? r_ : 0.2f*r_;
    }
    float cm = e;
    #pragma unroll
    for (int o = 4; o < 64; o <<= 1) cm = fmaxf(cm, __shfl_xor(cm, o));
    float nm = fmaxf(m, cm);
    float ex = act ? __expf(e - nm) : 0.f;
    #pragma unroll
    for (int o = 4; o < 64; o <<= 1) ex += __shfl_xor(ex, o);
    d = d * __expf(m - nm) + ex;
    m = nm;
  }
  d += 1e-16f;
  const float inv_d = 1.0f / d;

  // pass 2: weights + gather
  float a[16];
  #pragma unroll
  for (int q = 0; q < 16; ++q) a[q] = 0.f;
  const ushort* gbase = Gatt + col;
  for (int c0 = 0; c0 < deg; c0 += 16){
    int i = c0 + (l >> 2);
    int nc = min(16, deg - c0);
    float wv = 0.f; int sv = 0;
    if (i < deg){
      sv = csrc[beg + i];
      float r_ = als[(size_t)sv*4 + hh] + aldh;
      float e = r_ > 0.f ? r_ : 0.2f*r_;
      wv = __expf(e - m) * inv_d * cew[beg + i];
    }
    for (int jj = 0; jj < nc; ++jj){
      float wg = __shfl(wv, (jj << 2) | h2);
      int s    = __shfl(sv, jj << 2);
      const ushort* rp = gbase + (size_t)s*1024;
      s16x8 h0 = *(const s16x8*)rp;
      s16x8 h1 = *(const s16x8*)(rp + 8);
      #pragma unroll
      for (int q = 0; q < 8; ++q) a[q]   += wg * bf2f((ushort)h0[q]);
      #pragma unroll
      for (int q = 0; q < 8; ++q) a[q+8] += wg * bf2f((ushort)h1[q]);
    }
  }

  // epilogue: bias + linear-skip + GEMM-skip + ELU -> bf16
  s16x8 sk0 = *(const s16x8*)(Skip + (size_t)n*1024 + col);
  s16x8 sk1 = *(const s16x8*)(Skip + (size_t)n*1024 + col + 8);
  s16x8 ov0, ov1;
  #pragma unroll
  for (int q = 0; q < 8; ++q){
    float v = a[q] + bias[col+q] + lbias[col+q] + bf2f((ushort)sk0[q]);
    v = v > 0.f ? v : __expf(v) - 1.f;
    ov0[q] = (short)f2bf(v);
    float v2 = a[q+8] + bias[col+8+q] + lbias[col+8+q] + bf2f((ushort)sk1[q]);
    v2 = v2 > 0.f ? v2 : __expf(v2) - 1.f;
    ov1[q] = (short)f2bf(v2);
  }
  *(s16x8*)(Hout + (size_t)n*1024 + col)     = ov0;
  *(s16x8*)(Hout + (size_t)n*1024 + col + 8) = ov1;
}

// ---------------- layer 3: logits (H=6, C=10) ----------------
__global__ void k_al3(const ushort* __restrict__ G3, const float* __restrict__ a_s,
                      const float* __restrict__ a_d,
                      float* __restrict__ als, float* __restrict__ ald, int N){
  int n = blockIdx.x*256 + threadIdx.x;
  if (n >= N) return;
  const ushort* row = G3 + (size_t)n*60;
  #pragma unroll
  for (int h = 0; h < 6; ++h){
    float ps = 0.f, pd = 0.f;
    #pragma unroll
    for (int c = 0; c < 10; ++c){
      float v = bf2f(row[h*10 + c]);
      ps += v * a_s[h*10 + c];
      pd += v * a_d[h*10 + c];
    }
    als[(size_t)n*6 + h] = ps;
    ald[(size_t)n*6 + h] = pd;
  }
}

// ---------------- layer 3: edge-parallel online softmax + aggregate + mean ----------------
__global__ __launch_bounds__(64) void k_agg3(
    const ushort* __restrict__ G3,
    const ushort* __restrict__ Skip3,
    const float*  __restrict__ als,
    const float*  __restrict__ ald,
    const float*  __restrict__ b3,
    const float*  __restrict__ lb3,
    const int*    __restrict__ indptr,
    const int*    __restrict__ csrc,
    const float*  __restrict__ cew,
    float* __restrict__ out, int N)
{
  const int n = blockIdx.x;
  const int l = threadIdx.x;
  const int beg = indptr[n], deg = indptr[n+1] - beg;
  __shared__ float s_aldh[6];
  __shared__ int   s_src[64];
  __shared__ float s_wgt[64][6];
  __shared__ float s_o[6][10];
  if (l < 6) s_aldh[l] = ald[(size_t)n*6 + l];
  __syncthreads();
  float m0=-1e30f,m1=-1e30f,m2=-1e30f,m3=-1e30f,m4=-1e30f,m5=-1e30f;
  float d0=0.f,d1=0.f,d2=0.f,d3=0.f,d4=0.f,d5=0.f;
  for (int c0 = 0; c0 < deg; c0 += 64){
    int nc = min(64, deg - c0);
    bool act = l < nc;
    int s = act ? csrc[beg + c0 + l] : 0;
#define HP(hh, mm, dd) { \
    float e = -1e30f; \
    if (act){ float r_ = als[(size_t)s*6 + hh] + s_aldh[hh]; e = r_ > 0.f ? r_ : 0.2f*r_; } \
    float cm = e; \
    for (int o_ = 32; o_; o_ >>= 1) cm = fmaxf(cm, __shfl_xor(cm, o_)); \
    float nm = fmaxf(mm, cm); \
    float ex = act ? __expf(e - nm) : 0.f; \
    for (int o_ = 32; o_; o_ >>= 1) ex += __shfl_xor(ex, o_); \
    dd = dd * __expf(mm - nm) + ex; mm = nm; }
    HP(0,m0,d0) HP(1,m1,d1) HP(2,m2,d2) HP(3,m3,d3) HP(4,m4,d4) HP(5,m5,d5)
#undef HP
  }
  const int h = l / 10, c = l % 10;
  float o = 0.f;
  for (int c0 = 0; c0 < deg; c0 += 64){
    int nc = min(64, deg - c0);
    if (l < nc){
      int s = csrc[beg + c0 + l];
      s_src[l] = s;
      float w_ = cew[beg + c0 + l];
#define WP(hh, mm, dd) { \
      float r_ = als[(size_t)s*6 + hh] + s_aldh[hh]; \
      float e = r_ > 0.f ? r_ : 0.2f*r_; \
      s_wgt[l][hh] = __expf(e - mm) / (dd + 1e-16f) * w_; }
      WP(0,m0,d0) WP(1,m1,d1) WP(2,m2,d2) WP(3,m3,d3) WP(4,m4,d4) WP(5,m5,d5)
#undef WP
    }
    __syncthreads();
    if (l < 60){
      for (int i = 0; i < nc; ++i)
        o += s_wgt[i][h] * bf2f(G3[(size_t)s_src[i]*60 + l]);
    }
    __syncthreads();
  }
  if (l < 60) s_o[h][c] = o;
  __syncthreads();
  if (l < 10){
    float v = (s_o[0][l]+s_o[1][l]+s_o[2][l]+s_o[3][l]+s_o[4][l]+s_o[5][l]) * (1.0f/6.0f);
    v += b3[l] + lb3[l] + bf2f(Skip3[(size_t)n*10 + l]);
    out[(size_t)n*10 + l] = v;
  }
}

// ---------------- host ----------------
extern "C" void kernel_launch(void* const* d_in, const int* in_sizes, int n_in,
                              void* d_out, int out_size, void* d_ws, size_t ws_size,
                              hipStream_t stream)
{
  const int N = 20000, F = 128, E = 320000, ET = E + N;
  const int Mpad = 20224;            // 79*256 = 158*128
  const int F1 = 1024, NT = 2048;
  const int NWG1 = (Mpad/128)*(NT/128);   // 2528, %8==0
  const int NWG2 = (Mpad/256)*(NT/256);   // 632,  %8==0

  const float* x   = (const float*)d_in[0];
  const int*   ei  = (const int*)  d_in[1];
  const float* ew  = (const float*)d_in[2];
  const float* W1  = (const float*)d_in[3];
  const float* a1s = (const float*)d_in[4];
  const float* a1d = (const float*)d_in[5];
  const float* b1  = (const float*)d_in[6];
  const float* lw1 = (const float*)d_in[7];
  const float* lb1 = (const float*)d_in[8];
  const float* W2  = (const float*)d_in[9];
  const float* a2s = (const float*)d_in[10];
  const float* a2d = (const float*)d_in[11];
  const float* b2  = (const float*)d_in[12];
  const float* lw2 = (const float*)d_in[13];
  const float* lb2 = (const float*)d_in[14];
  const float* W3  = (const float*)d_in[15];
  const float* a3s = (const float*)d_in[16];
  const float* a3d = (const float*)d_in[17];
  const float* b3  = (const float*)d_in[18];
  const float* lw3 = (const float*)d_in[19];
  const float* lb3 = (const float*)d_in[20];

  char* ws = (char*)d_ws;
  size_t off = 0;
  auto alloc = [&](size_t bytes) -> void* {
    void* p = ws + off;
    off = (off + bytes + 255) & ~(size_t)255;
    return p;
  };
  ushort* Gatt = (ushort*)alloc((size_t)Mpad*F1*2);
  ushort* Skip = (ushort*)alloc((size_t)Mpad*F1*2);
  ushort* H    = (ushort*)alloc((size_t)Mpad*F1*2);
  ushort* xb   = (ushort*)alloc((size_t)Mpad*F*2);
  ushort* BT   = (ushort*)alloc((size_t)NT*1024*2);
  float*  als  = (float*) alloc((size_t)N*6*4);
  float*  ald  = (float*) alloc((size_t)N*6*4);
  int*    counts = (int*)alloc((size_t)2*N*4);
  int*    cursor = counts + N;
  int*    indptr = (int*)alloc((size_t)(N+1)*4);
  int*    csrc   = (int*)alloc((size_t)ET*4);
  float*  cew    = (float*)alloc((size_t)ET*4);
  if (off > ws_size) return;

  hipMemsetAsync(counts, 0, (size_t)2*N*4, stream);
  k_count<<<(ET+255)/256, 256, 0, stream>>>(ei, counts, E, ET);
  k_scan<<<1, 1024, 0, stream>>>(counts, indptr, N);
  k_fill<<<(ET+255)/256, 256, 0, stream>>>(ei, ew, indptr, cursor, csrc, cew, E, ET);
  k_f2b<<<(Mpad*F/8+255)/256, 256, 0, stream>>>(x, xb, N*F/8, Mpad*F/8);

  // ---- layer 1 (128^2 path) ----
  k_packB<<<dim3((F+31)/32, NT/32), 256, 0, stream>>>(W1, lw1, BT, F, 1024, 1024, NT);
  k_gemm<<<dim3(NWG1), 256, 0, stream>>>(xb, BT, Gatt, Skip, F, 1024, 1024, NT/128, NWG1/8);
  k_al<<<(N+3)/4, 256, 0, stream>>>(Gatt, a1s, a1d, als, ald, N);
  k_agg<<<Mpad/4, 256, 0, stream>>>(Gatt, Skip, als, ald, b1, lb1, indptr, csrc, cew, H, N);

  // ---- layer 2 (8-phase 256^2 path, v4) ----
  k_packB<<<dim3(F1/32, NT/32), 256, 0, stream>>>(W2, lw2, BT, F1, 1024, 1024, NT);
  k_gemm8<<<dim3(NWG2), 512, 0, stream>>>(H, BT, Gatt, Skip, F1, 1024, NWG2/8);
  k_al<<<(N+3)/4, 256, 0, stream>>>(Gatt, a2s, a2d, als, ald, N);
  k_agg<<<Mpad/4, 256, 0, stream>>>(Gatt, Skip, als, ald, b2, lb2, indptr, csrc, cew, H, N);

  // ---- layer 3 (128^2 path) ----
  k_packB<<<dim3(F1/32, 128/32), 256, 0, stream>>>(W3, lw3, BT, F1, 60, 10, 128);
  k_gemm<<<dim3(Mpad/128), 256, 0, stream>>>(H, BT, Gatt, Skip, F1, 60, 10, 1, 0);
  k_al3<<<(N+255)/256, 256, 0, stream>>>(Gatt, a3s, a3d, als, ald, N);
  k_agg3<<<N, 64, 0, stream>>>(Gatt, Skip, als, ald, b3, lb3, indptr, csrc, cew,
                               (float*)d_out, N);
}

// Round 10
// 499.622 us; speedup vs baseline: 1.0366x; 1.0041x over previous
//
#include <hip/hip_runtime.h>

typedef __attribute__((ext_vector_type(8))) short s16x8;
typedef __attribute__((ext_vector_type(8))) __bf16 bf16x8;
typedef __attribute__((ext_vector_type(4))) float f32x4;

__device__ inline float bf2f(ushort u){ return __uint_as_float(((unsigned)u)<<16); }
__device__ inline ushort f2bf(float f){
  unsigned u = __float_as_uint(f);
  unsigned r = (u + 0x7fffu + ((u>>16)&1u)) >> 16;
  return (ushort)r;
}

__device__ inline void gl_lds16(const ushort* g, ushort* l){
  __builtin_amdgcn_global_load_lds(
      (const __attribute__((address_space(1))) unsigned int*)g,
      (__attribute__((address_space(3))) unsigned int*)l,
      16, 0, 0);
}

// ---------------- CSR build ----------------
__global__ void k_count(const int* __restrict__ ei, int* __restrict__ counts,
                        int E, int ET){
  int e = blockIdx.x*256 + threadIdx.x;
  if (e >= ET) return;
  int dst = (e < E) ? ei[E + e] : (e - E);
  atomicAdd(&counts[dst], 1);
}

__global__ __launch_bounds__(1024) void k_scan(const int* __restrict__ cnt,
                                               int* __restrict__ indptr, int N){
  __shared__ int part[1024];
  int t = threadIdx.x;
  int per = (N + 1023) / 1024;
  int base = t * per;
  int s = 0;
  for (int i = 0; i < per; ++i){ int idx = base + i; if (idx < N) s += cnt[idx]; }
  part[t] = s; __syncthreads();
  for (int off = 1; off < 1024; off <<= 1){
    int v = (t >= off) ? part[t-off] : 0;
    __syncthreads();
    if (t >= off) part[t] += v;
    __syncthreads();
  }
  int run = (t == 0) ? 0 : part[t-1];
  for (int i = 0; i < per; ++i){
    int idx = base + i;
    if (idx < N){ indptr[idx] = run; run += cnt[idx]; }
  }
  if (t == 1023) indptr[N] = run;
}

__global__ void k_fill(const int* __restrict__ ei, const float* __restrict__ ew,
                       const int* __restrict__ indptr, int* __restrict__ cursor,
                       int* __restrict__ csrc, float* __restrict__ cew,
                       int E, int ET){
  int e = blockIdx.x*256 + threadIdx.x;
  if (e >= ET) return;
  int src, dst; float w;
  if (e < E){ src = ei[e]; dst = ei[E + e]; w = ew[e]; }
  else { src = dst = e - E; w = 1.0f; }
  int pos = indptr[dst] + atomicAdd(&cursor[dst], 1);
  csrc[pos] = src; cew[pos] = w;
}

// ---------------- conversions / packing ----------------
__global__ void k_f2b(const float* __restrict__ x, ushort* __restrict__ xb,
                      int n8valid, int n8total){
  int i = blockIdx.x*256 + threadIdx.x;
  if (i >= n8total) return;
  s16x8 o = {0,0,0,0,0,0,0,0};
  if (i < n8valid){
    const float4* p = (const float4*)x + (size_t)i*2;
    float4 a = p[0], b = p[1];
    o[0]=(short)f2bf(a.x); o[1]=(short)f2bf(a.y); o[2]=(short)f2bf(a.z); o[3]=(short)f2bf(a.w);
    o[4]=(short)f2bf(b.x); o[5]=(short)f2bf(b.y); o[6]=(short)f2bf(b.z); o[7]=(short)f2bf(b.w);
  }
  *((s16x8*)xb + i) = o;
}

__global__ __launch_bounds__(256) void k_packB(
    const float* __restrict__ W, const float* __restrict__ LW,
    ushort* __restrict__ BT, int K, int NW, int NL, int Npad)
{
  __shared__ float tile[32][33];
  int k0 = blockIdx.x*32, n0 = blockIdx.y*32;
  int c = threadIdx.x & 31, r4 = threadIdx.x >> 5;
  #pragma unroll
  for (int rr = 0; rr < 32; rr += 8){
    int k = k0 + r4 + rr, n = n0 + c;
    float v = 0.f;
    if (k < K){
      if (n < NW)            v = W[(size_t)k*NW + n];
      else if (n < NW + NL)  v = LW[(size_t)k*NL + (n - NW)];
    }
    tile[r4+rr][c] = v;
  }
  __syncthreads();
  #pragma unroll
  for (int rr = 0; rr < 32; rr += 8){
    int n = n0 + r4 + rr, k = k0 + c;
    if (n < Npad && k < K) BT[(size_t)n*K + k] = f2bf(tile[c][r4+rr]);
  }
}

// ---------------- 128^2 MFMA GEMM (layer 1): proven R3 structure ----------------
__global__ __launch_bounds__(256) void k_gemm(
    const ushort* __restrict__ A, const ushort* __restrict__ BT,
    ushort* __restrict__ Gatt, ushort* __restrict__ Skip,
    int K, int GW, int SW, int NCB, int CPX)
{
  __shared__ ushort As[128*64];
  __shared__ ushort Bs[128*64];
  const int bid = blockIdx.x;
  const int lb = CPX ? ((bid & 7)*CPX + (bid >> 3)) : bid;
  const size_t row0 = (size_t)(lb / NCB) * 128;
  const size_t col0 = (size_t)(lb % NCB) * 128;
  const int t = threadIdx.x;
  const int l = t & 63, w = t >> 6;
  const int wr = w >> 1, wc = w & 1;
  const int sr = l >> 3;
  const int sk = ((l & 7) ^ sr) << 3;
  const ushort* gA = A  + (row0 + w*8 + sr)*(size_t)K + sk;
  const ushort* gB = BT + (col0 + w*8 + sr)*(size_t)K + sk;
  ushort* lA = As + w*512;
  ushort* lB = Bs + w*512;
  const int rf = l & 15;
  const int g4 = l >> 4;
  f32x4 acc[4][4] = {};

  for (int k0 = 0; k0 < K; k0 += 64){
    #pragma unroll
    for (int i = 0; i < 4; ++i){
      gl_lds16(gA + k0 + (size_t)(i*32)*K, lA + i*2048);
      gl_lds16(gB + k0 + (size_t)(i*32)*K, lB + i*2048);
    }
    __syncthreads();
    #pragma unroll
    for (int kk = 0; kk < 2; ++kk){
      const int koff = ((((kk<<2) | g4) ^ (rf & 7)) << 3);
      bf16x8 af[4], bfr[4];
      #pragma unroll
      for (int i = 0; i < 4; ++i)
        af[i] = __builtin_bit_cast(bf16x8, *(const s16x8*)(As + (wr*64 + i*16 + rf)*64 + koff));
      #pragma unroll
      for (int j = 0; j < 4; ++j)
        bfr[j] = __builtin_bit_cast(bf16x8, *(const s16x8*)(Bs + (wc*64 + j*16 + rf)*64 + koff));
      #pragma unroll
      for (int i = 0; i < 4; ++i)
        #pragma unroll
        for (int j = 0; j < 4; ++j)
          acc[i][j] = __builtin_amdgcn_mfma_f32_16x16x32_bf16(af[i], bfr[j], acc[i][j], 0, 0, 0);
    }
    __syncthreads();
  }

  #pragma unroll
  for (int i = 0; i < 4; ++i){
    #pragma unroll
    for (int j = 0; j < 4; ++j){
      int gc = (int)col0 + wc*64 + j*16 + rf;
      #pragma unroll
      for (int r = 0; r < 4; ++r){
        size_t gr = row0 + wr*64 + i*16 + (g4<<2) + r;
        float v = acc[i][j][r];
        if (gc < GW)            Gatt[gr*GW + gc] = f2bf(v);
        else if (gc < GW + SW)  Skip[gr*SW + (gc - GW)] = f2bf(v);
      }
    }
  }
}

// ---------------- split-K 128^2 GEMM (layer 3): K-slice -> f32 partials ----------------
// grid = (Mpad/128)*4 blocks; bid&3 = K-part, bid>>2 = row tile. col0 = 0 (128 cols).
__global__ __launch_bounds__(256) void k_gemm_sk(
    const ushort* __restrict__ A, const ushort* __restrict__ BT,
    float* __restrict__ P, int K, int kseg, int Mpad)
{
  __shared__ ushort As[128*64];
  __shared__ ushort Bs[128*64];
  const int bid = blockIdx.x;
  const int part = bid & 3;
  const size_t row0 = (size_t)(bid >> 2) * 128;
  const int kbeg = part * kseg;
  const int kend = kbeg + kseg;
  const int t = threadIdx.x;
  const int l = t & 63, w = t >> 6;
  const int wr = w >> 1, wc = w & 1;
  const int sr = l >> 3;
  const int sk = ((l & 7) ^ sr) << 3;
  const ushort* gA = A  + (row0 + w*8 + sr)*(size_t)K + sk;
  const ushort* gB = BT + (w*8 + sr)*(size_t)K + sk;
  ushort* lA = As + w*512;
  ushort* lB = Bs + w*512;
  const int rf = l & 15;
  const int g4 = l >> 4;
  f32x4 acc[4][4] = {};

  for (int k0 = kbeg; k0 < kend; k0 += 64){
    #pragma unroll
    for (int i = 0; i < 4; ++i){
      gl_lds16(gA + k0 + (size_t)(i*32)*K, lA + i*2048);
      gl_lds16(gB + k0 + (size_t)(i*32)*K, lB + i*2048);
    }
    __syncthreads();
    #pragma unroll
    for (int kk = 0; kk < 2; ++kk){
      const int koff = ((((kk<<2) | g4) ^ (rf & 7)) << 3);
      bf16x8 af[4], bfr[4];
      #pragma unroll
      for (int i = 0; i < 4; ++i)
        af[i] = __builtin_bit_cast(bf16x8, *(const s16x8*)(As + (wr*64 + i*16 + rf)*64 + koff));
      #pragma unroll
      for (int j = 0; j < 4; ++j)
        bfr[j] = __builtin_bit_cast(bf16x8, *(const s16x8*)(Bs + (wc*64 + j*16 + rf)*64 + koff));
      #pragma unroll
      for (int i = 0; i < 4; ++i)
        #pragma unroll
        for (int j = 0; j < 4; ++j)
          acc[i][j] = __builtin_amdgcn_mfma_f32_16x16x32_bf16(af[i], bfr[j], acc[i][j], 0, 0, 0);
    }
    __syncthreads();
  }

  float* Pp = P + (size_t)part * Mpad * 128;
  #pragma unroll
  for (int i = 0; i < 4; ++i){
    #pragma unroll
    for (int j = 0; j < 4; ++j){
      int gc = wc*64 + j*16 + rf;
      #pragma unroll
      for (int r = 0; r < 4; ++r){
        size_t gr = row0 + wr*64 + i*16 + (g4<<2) + r;
        Pp[gr*128 + gc] = acc[i][j][r];
      }
    }
  }
}

// reduce 4 partials -> G3 (60-col bf16) + Skip3 (10-col bf16)
__global__ void k_red3(const float* __restrict__ P, ushort* __restrict__ G3,
                       ushort* __restrict__ S3, int Mpad){
  int idx = blockIdx.x*256 + threadIdx.x;
  int row = idx >> 7, gc = idx & 127;
  if (row >= Mpad || gc >= 70) return;
  const size_t st = (size_t)Mpad*128;
  float v = P[idx] + P[idx+st] + P[idx+2*st] + P[idx+3*st];
  if (gc < 60) G3[(size_t)row*60 + gc] = f2bf(v);
  else         S3[(size_t)row*10 + (gc-60)] = f2bf(v);
}

// ---------------- 8-phase 256^2 MFMA GEMM v4 (layer 2) ----------------
#define STG8(p0, hh, ktv, offU) do { \
  const ushort* _g = (p0) + (((size_t)(hh))<<7)*(size_t)K + (((size_t)(ktv))<<6); \
  gl_lds16(_g, S + (offU) + (w<<9)); \
  gl_lds16(_g + ((size_t)K<<6), S + (offU) + 4096 + (w<<9)); \
} while(0)

#define RD_A(base_) do { _Pragma("unroll") \
  for (int i_ = 0; i_ < 4; ++i_){ \
    const int hr = wr*64 + i_*16 + rf; const int sw = hr & 7; \
    av[i_][0] = *(const bf16x8*)((base_) + hr*64 + ((g4 ^ sw) << 3)); \
    av[i_][1] = *(const bf16x8*)((base_) + hr*64 + (((4|g4) ^ sw) << 3)); } \
} while(0)

#define RD_B(base_, dst_) do { _Pragma("unroll") \
  for (int j_ = 0; j_ < 2; ++j_){ \
    const int cf = wc*32 + j_*16 + rf; const int sw = cf & 7; \
    dst_[j_][0] = *(const bf16x8*)((base_) + cf*64 + ((g4 ^ sw) << 3)); \
    dst_[j_][1] = *(const bf16x8*)((base_) + cf*64 + (((4|g4) ^ sw) << 3)); } \
} while(0)

#define MM8(mh, nh, bv_) do { \
  __builtin_amdgcn_s_setprio(1); \
  _Pragma("unroll") \
  for (int kk_ = 0; kk_ < 2; ++kk_) \
    _Pragma("unroll") \
    for (int i_ = 0; i_ < 4; ++i_) \
      _Pragma("unroll") \
      for (int j_ = 0; j_ < 2; ++j_) \
        acc[mh][nh][i_][j_] = __builtin_amdgcn_mfma_f32_16x16x32_bf16( \
            av[i_][kk_], bv_[j_][kk_], acc[mh][nh][i_][j_], 0, 0, 0); \
  __builtin_amdgcn_s_setprio(0); \
} while(0)

__global__ __launch_bounds__(512, 1) void k_gemm8(
    const ushort* __restrict__ A, const ushort* __restrict__ BT,
    ushort* __restrict__ Gatt, ushort* __restrict__ Skip,
    int K, int GW, int CPX)
{
  __shared__ ushort S[65536];
  const int bid = blockIdx.x;
  const int lb = (bid & 7)*CPX + (bid >> 3);
  const size_t row0 = (size_t)(lb >> 3) * 256;
  const size_t col0 = (size_t)(lb & 7) * 256;
  const int t = threadIdx.x;
  const int l = t & 63, w = t >> 6;
  const int wr = w >> 2, wc = w & 3;
  const int rf = l & 15, g4 = l >> 4;
  const int T = K >> 6;

  const int r0 = t >> 3, s0 = t & 7;
  const ushort* pA = A  + (row0 + r0)*(size_t)K + ((s0 ^ (r0 & 7)) << 3);
  const ushort* pB = BT + (col0 + r0)*(size_t)K + ((s0 ^ (r0 & 7)) << 3);

  f32x4 acc[2][2][4][2] = {};
  bf16x8 av[4][2], bvlo[2][2], bvhi[2][2];

  STG8(pA, 0, 0, 0);
  STG8(pB, 0, 0, 16384);
  STG8(pA, 1, 0, 8192);
  STG8(pB, 1, 0, 24576);
  STG8(pA, 0, 1, 32768);
  STG8(pB, 0, 1, 49152);
  asm volatile("s_waitcnt vmcnt(4)");
  asm volatile("s_barrier" ::: "memory");

  for (int u = 0; u < T; ++u){
    const int b = u & 1;
    const int bbase = b << 15;
    const int nbase = bbase ^ 32768;
    const bool un1 = (u + 1 < T), un2 = (u + 2 < T);
    const ushort* Alo = S + bbase;
    const ushort* Ahi = S + bbase + 8192;
    const ushort* Blo = S + bbase + 16384;
    const ushort* Bhi = S + bbase + 24576;
    RD_A(Alo); RD_B(Blo, bvlo);
    if (un1) STG8(pA, 1, u+1, nbase + 8192);
    MM8(0, 0, bvlo);
    asm volatile("s_barrier" ::: "memory");
    RD_B(Bhi, bvhi);
    if (un1) STG8(pB, 1, u+1, nbase + 24576);
    MM8(0, 1, bvhi);
    asm volatile("s_barrier" ::: "memory");
    RD_A(Ahi);
    if (un2) STG8(pA, 0, u+2, bbase);
    MM8(1, 1, bvhi);
    asm volatile("s_barrier" ::: "memory");
    if (un2) STG8(pB, 0, u+2, bbase + 16384);
    MM8(1, 0, bvlo);
    if (un2) asm volatile("s_waitcnt vmcnt(4)");
    else     asm volatile("s_waitcnt vmcnt(0)");
    asm volatile("s_barrier" ::: "memory");
  }

  ushort* outp; int cb;
  if ((int)col0 < GW){ outp = Gatt; cb = (int)col0; }
  else               { outp = Skip; cb = (int)col0 - GW; }
  #pragma unroll
  for (int mh = 0; mh < 2; ++mh)
    #pragma unroll
    for (int i = 0; i < 4; ++i)
      #pragma unroll
      for (int rr = 0; rr < 4; ++rr){
        size_t gr = row0 + mh*128 + wr*64 + i*16 + (g4<<2) + rr;
        ushort* rp = outp + gr*1024 + cb;
        #pragma unroll
        for (int nh = 0; nh < 2; ++nh)
          #pragma unroll
          for (int j = 0; j < 2; ++j)
            rp[nh*128 + wc*32 + j*16 + rf] = f2bf(acc[mh][nh][i][j][rr]);
      }
}

// ---------------- attention logits (layers 1-2: H=4, C=256) ----------------
__global__ __launch_bounds__(256) void k_al(const ushort* __restrict__ Gatt,
    const float* __restrict__ a_s, const float* __restrict__ a_d,
    float* __restrict__ als, float* __restrict__ ald, int N){
  int gw = (blockIdx.x*blockDim.x + threadIdx.x) >> 6;
  int l = threadIdx.x & 63;
  if (gw >= N) return;
  const ushort* row = Gatt + (size_t)gw*1024;
  int c0 = l*16;
  s16x8 v0 = *(const s16x8*)(row + c0);
  s16x8 v1 = *(const s16x8*)(row + c0 + 8);
  float ps = 0.f, pd = 0.f;
  #pragma unroll
  for (int q = 0; q < 8; ++q){
    float f0 = bf2f((ushort)v0[q]), f1 = bf2f((ushort)v1[q]);
    ps += f0*a_s[c0+q] + f1*a_s[c0+8+q];
    pd += f0*a_d[c0+q] + f1*a_d[c0+8+q];
  }
  #pragma unroll
  for (int off = 8; off; off >>= 1){
    ps += __shfl_down(ps, off);
    pd += __shfl_down(pd, off);
  }
  if ((l & 15) == 0){
    als[(size_t)gw*4 + (l>>4)] = ps;
    ald[(size_t)gw*4 + (l>>4)] = pd;
  }
}

// ---------------- softmax + aggregate + bias + skip + ELU: wave-per-node ----------------
__global__ __launch_bounds__(256) void k_agg(
    const ushort* __restrict__ Gatt,
    const ushort* __restrict__ Skip,
    const float*  __restrict__ als,
    const float*  __restrict__ ald,
    const float*  __restrict__ bias,
    const float*  __restrict__ lbias,
    const int*    __restrict__ indptr,
    const int*    __restrict__ csrc,
    const float*  __restrict__ cew,
    ushort* __restrict__ Hout,
    int N)
{
  const int t = threadIdx.x;
  const int l = t & 63, w = t >> 6;
  const int n = blockIdx.x*4 + w;
  const int h2 = l >> 4;
  const int col = l*16;
  if (n >= N){
    s16x8 z = {0,0,0,0,0,0,0,0};
    *(s16x8*)(Hout + (size_t)n*1024 + col)     = z;
    *(s16x8*)(Hout + (size_t)n*1024 + col + 8) = z;
    return;
  }
  const int beg = indptr[n];
  const int deg = indptr[n+1] - beg;
  const int hh = l & 3;
  const float aldh = ald[(size_t)n*4 + hh];

  // pass 1: online per-head max / denominator (lane tracks head hh)
  float m = -1e30f, d = 0.f;
  for (int c0 = 0; c0 < deg; c0 += 16){
    int i = c0 + (l >> 2);
    bool act = (i < deg);
    float e = -1e30f;
    if (act){
      int s = csrc[beg + i];
      float r_ = als[(size_t)s*4 + hh] + aldh;
      e = r_ > 0.f ? r_ : 0.2f*r_;
    }
    float cm = e;
    #pragma unroll
    for (int o = 4; o < 64; o <<= 1) cm = fmaxf(cm, __shfl_xor(cm, o));
    float nm = fmaxf(m, cm);
    float ex = act ? __expf(e - nm) : 0.f;
    #pragma unroll
    for (int o = 4; o < 64; o <<= 1) ex += __shfl_xor(ex, o);
    d = d * __expf(m - nm) + ex;
    m = nm;
  }
  d += 1e-16f;
  const float inv_d = 1.0f / d;

  // pass 2: weights + gather (2 edges in flight)
  float a[16];
  #pragma unroll
  for (int q = 0; q < 16; ++q) a[q] = 0.f;
  const ushort* gbase = Gatt + col;
  for (int c0 = 0; c0 < deg; c0 += 16){
    int i = c0 + (l >> 2);
    int nc = min(16, deg - c0);
    float wv = 0.f; int sv = 0;
    if (i < deg){
      sv = csrc[beg + i];
      float r_ = als[(size_t)sv*4 + hh] + aldh;
      float e = r_ > 0.f ? r_ : 0.2f*r_;
      wv = __expf(e - m) * inv_d * cew[beg + i];
    }
    int jj = 0;
    for (; jj + 1 < nc; jj += 2){
      float wg0 = __shfl(wv, (jj << 2) | h2);
      int   sg0 = __shfl(sv, jj << 2);
      float wg1 = __shfl(wv, ((jj+1) << 2) | h2);
      int   sg1 = __shfl(sv, (jj+1) << 2);
      const ushort* rp0 = gbase + (size_t)sg0*1024;
      const ushort* rp1 = gbase + (size_t)sg1*1024;
      s16x8 x0 = *(const s16x8*)rp0;
      s16x8 x1 = *(const s16x8*)(rp0 + 8);
      s16x8 y0 = *(const s16x8*)rp1;
      s16x8 y1 = *(const s16x8*)(rp1 + 8);
      #pragma unroll
      for (int q = 0; q < 8; ++q){
        a[q]   += wg0 * bf2f((ushort)x0[q]) + wg1 * bf2f((ushort)y0[q]);
        a[q+8] += wg0 * bf2f((ushort)x1[q]) + wg1 * bf2f((ushort)y1[q]);
      }
    }
    if (jj < nc){
      float wg = __shfl(wv, (jj << 2) | h2);
      int   s  = __shfl(sv, jj << 2);
      const ushort* rp = gbase + (size_t)s*1024;
      s16x8 h0 = *(const s16x8*)rp;
      s16x8 h1 = *(const s16x8*)(rp + 8);
      #pragma unroll
      for (int q = 0; q < 8; ++q){
        a[q]   += wg * bf2f((ushort)h0[q]);
        a[q+8] += wg * bf2f((ushort)h1[q]);
      }
    }
  }

  s16x8 sk0 = *(const s16x8*)(Skip + (size_t)n*1024 + col);
  s16x8 sk1 = *(const s16x8*)(Skip + (size_t)n*1024 + col + 8);
  s16x8 ov0, ov1;
  #pragma unroll
  for (int q = 0; q < 8; ++q){
    float v = a[q] + bias[col+q] + lbias[col+q] + bf2f((ushort)sk0[q]);
    v = v > 0.f ? v : __expf(v) - 1.f;
    ov0[q] = (short)f2bf(v);
    float v2 = a[q+8] + bias[col+8+q] + lbias[col+8+q] + bf2f((ushort)sk1[q]);
    v2 = v2 > 0.f ? v2 : __expf(v2) - 1.f;
    ov1[q] = (short)f2bf(v2);
  }
  *(s16x8*)(Hout + (size_t)n*1024 + col)     = ov0;
  *(s16x8*)(Hout + (size_t)n*1024 + col + 8) = ov1;
}

// ---------------- layer 3: logits (H=6, C=10) ----------------
__global__ void k_al3(const ushort* __restrict__ G3, const float* __restrict__ a_s,
                      const float* __restrict__ a_d,
                      float* __restrict__ als, float* __restrict__ ald, int N){
  int n = blockIdx.x*256 + threadIdx.x;
  if (n >= N) return;
  const ushort* row = G3 + (size_t)n*60;
  #pragma unroll
  for (int h = 0; h < 6; ++h){
    float ps = 0.f, pd = 0.f;
    #pragma unroll
    for (int c = 0; c < 10; ++c){
      float v = bf2f(row[h*10 + c]);
      ps += v * a_s[h*10 + c];
      pd += v * a_d[h*10 + c];
    }
    als[(size_t)n*6 + h] = ps;
    ald[(size_t)n*6 + h] = pd;
  }
}

// ---------------- layer 3: edge-parallel online softmax + aggregate + mean ----------------
__global__ __launch_bounds__(64) void k_agg3(
    const ushort* __restrict__ G3,
    const ushort* __restrict__ Skip3,
    const float*  __restrict__ als,
    const float*  __restrict__ ald,
    const float*  __restrict__ b3,
    const float*  __restrict__ lb3,
    const int*    __restrict__ indptr,
    const int*    __restrict__ csrc,
    const float*  __restrict__ cew,
    float* __restrict__ out, int N)
{
  const int n = blockIdx.x;
  const int l = threadIdx.x;
  const int beg = indptr[n], deg = indptr[n+1] - beg;
  __shared__ float s_aldh[6];
  __shared__ int   s_src[64];
  __shared__ float s_wgt[64][6];
  __shared__ float s_o[6][10];
  if (l < 6) s_aldh[l] = ald[(size_t)n*6 + l];
  __syncthreads();
  float m0=-1e30f,m1=-1e30f,m2=-1e30f,m3=-1e30f,m4=-1e30f,m5=-1e30f;
  float d0=0.f,d1=0.f,d2=0.f,d3=0.f,d4=0.f,d5=0.f;
  for (int c0 = 0; c0 < deg; c0 += 64){
    int nc = min(64, deg - c0);
    bool act = l < nc;
    int s = act ? csrc[beg + c0 + l] : 0;
#define HP(hh, mm, dd) { \
    float e = -1e30f; \
    if (act){ float r_ = als[(size_t)s*6 + hh] + s_aldh[hh]; e = r_ > 0.f ? r_ : 0.2f*r_; } \
    float cm = e; \
    for (int o_ = 32; o_; o_ >>= 1) cm = fmaxf(cm, __shfl_xor(cm, o_)); \
    float nm = fmaxf(mm, cm); \
    float ex = act ? __expf(e - nm) : 0.f; \
    for (int o_ = 32; o_; o_ >>= 1) ex += __shfl_xor(ex, o_); \
    dd = dd * __expf(mm - nm) + ex; mm = nm; }
    HP(0,m0,d0) HP(1,m1,d1) HP(2,m2,d2) HP(3,m3,d3) HP(4,m4,d4) HP(5,m5,d5)
#undef HP
  }
  const int h = l / 10, c = l % 10;
  float o = 0.f;
  for (int c0 = 0; c0 < deg; c0 += 64){
    int nc = min(64, deg - c0);
    if (l < nc){
      int s = csrc[beg + c0 + l];
      s_src[l] = s;
      float w_ = cew[beg + c0 + l];
#define WP(hh, mm, dd) { \
      float r_ = als[(size_t)s*6 + hh] + s_aldh[hh]; \
      float e = r_ > 0.f ? r_ : 0.2f*r_; \
      s_wgt[l][hh] = __expf(e - mm) / (dd + 1e-16f) * w_; }
      WP(0,m0,d0) WP(1,m1,d1) WP(2,m2,d2) WP(3,m3,d3) WP(4,m4,d4) WP(5,m5,d5)
#undef WP
    }
    __syncthreads();
    if (l < 60){
      for (int i = 0; i < nc; ++i)
        o += s_wgt[i][h] * bf2f(G3[(size_t)s_src[i]*60 + l]);
    }
    __syncthreads();
  }
  if (l < 60) s_o[h][c] = o;
  __syncthreads();
  if (l < 10){
    float v = (s_o[0][l]+s_o[1][l]+s_o[2][l]+s_o[3][l]+s_o[4][l]+s_o[5][l]) * (1.0f/6.0f);
    v += b3[l] + lb3[l] + bf2f(Skip3[(size_t)n*10 + l]);
    out[(size_t)n*10 + l] = v;
  }
}

// ---------------- host ----------------
extern "C" void kernel_launch(void* const* d_in, const int* in_sizes, int n_in,
                              void* d_out, int out_size, void* d_ws, size_t ws_size,
                              hipStream_t stream)
{
  const int N = 20000, F = 128, E = 320000, ET = E + N;
  const int Mpad = 20224;            // 79*256 = 158*128
  const int F1 = 1024, NT = 2048;
  const int NWG1 = (Mpad/128)*(NT/128);   // 2528, %8==0
  const int NWG2 = (Mpad/256)*(NT/256);   // 632,  %8==0

  const float* x   = (const float*)d_in[0];
  const int*   ei  = (const int*)  d_in[1];
  const float* ew  = (const float*)d_in[2];
  const float* W1  = (const float*)d_in[3];
  const float* a1s = (const float*)d_in[4];
  const float* a1d = (const float*)d_in[5];
  const float* b1  = (const float*)d_in[6];
  const float* lw1 = (const float*)d_in[7];
  const float* lb1 = (const float*)d_in[8];
  const float* W2  = (const float*)d_in[9];
  const float* a2s = (const float*)d_in[10];
  const float* a2d = (const float*)d_in[11];
  const float* b2  = (const float*)d_in[12];
  const float* lw2 = (const float*)d_in[13];
  const float* lb2 = (const float*)d_in[14];
  const float* W3  = (const float*)d_in[15];
  const float* a3s = (const float*)d_in[16];
  const float* a3d = (const float*)d_in[17];
  const float* b3  = (const float*)d_in[18];
  const float* lw3 = (const float*)d_in[19];
  const float* lb3 = (const float*)d_in[20];

  char* ws = (char*)d_ws;
  size_t off = 0;
  auto alloc = [&](size_t bytes) -> void* {
    void* p = ws + off;
    off = (off + bytes + 255) & ~(size_t)255;
    return p;
  };
  ushort* Gatt = (ushort*)alloc((size_t)Mpad*F1*2);
  ushort* Skip = (ushort*)alloc((size_t)Mpad*F1*2);
  ushort* H    = (ushort*)alloc((size_t)Mpad*F1*2);
  ushort* xb   = (ushort*)alloc((size_t)Mpad*F*2);
  ushort* BT   = (ushort*)alloc((size_t)NT*1024*2);
  float*  P    = (float*) alloc((size_t)4*Mpad*128*4);  // split-K partials (41 MB)
  float*  als  = (float*) alloc((size_t)N*6*4);
  float*  ald  = (float*) alloc((size_t)N*6*4);
  int*    counts = (int*)alloc((size_t)2*N*4);
  int*    cursor = counts + N;
  int*    indptr = (int*)alloc((size_t)(N+1)*4);
  int*    csrc   = (int*)alloc((size_t)ET*4);
  float*  cew    = (float*)alloc((size_t)ET*4);
  if (off > ws_size) return;

  hipMemsetAsync(counts, 0, (size_t)2*N*4, stream);
  k_count<<<(ET+255)/256, 256, 0, stream>>>(ei, counts, E, ET);
  k_scan<<<1, 1024, 0, stream>>>(counts, indptr, N);
  k_fill<<<(ET+255)/256, 256, 0, stream>>>(ei, ew, indptr, cursor, csrc, cew, E, ET);
  k_f2b<<<(Mpad*F/8+255)/256, 256, 0, stream>>>(x, xb, N*F/8, Mpad*F/8);

  // ---- layer 1 (128^2 path) ----
  k_packB<<<dim3((F+31)/32, NT/32), 256, 0, stream>>>(W1, lw1, BT, F, 1024, 1024, NT);
  k_gemm<<<dim3(NWG1), 256, 0, stream>>>(xb, BT, Gatt, Skip, F, 1024, 1024, NT/128, NWG1/8);
  k_al<<<(N+3)/4, 256, 0, stream>>>(Gatt, a1s, a1d, als, ald, N);
  k_agg<<<Mpad/4, 256, 0, stream>>>(Gatt, Skip, als, ald, b1, lb1, indptr, csrc, cew, H, N);

  // ---- layer 2 (8-phase 256^2 path, v4) ----
  k_packB<<<dim3(F1/32, NT/32), 256, 0, stream>>>(W2, lw2, BT, F1, 1024, 1024, NT);
  k_gemm8<<<dim3(NWG2), 512, 0, stream>>>(H, BT, Gatt, Skip, F1, 1024, NWG2/8);
  k_al<<<(N+3)/4, 256, 0, stream>>>(Gatt, a2s, a2d, als, ald, N);
  k_agg<<<Mpad/4, 256, 0, stream>>>(Gatt, Skip, als, ald, b2, lb2, indptr, csrc, cew, H, N);

  // ---- layer 3 (split-K path) ----
  k_packB<<<dim3(F1/32, 128/32), 256, 0, stream>>>(W3, lw3, BT, F1, 60, 10, 128);
  k_gemm_sk<<<dim3((Mpad/128)*4), 256, 0, stream>>>(H, BT, P, F1, F1/4, Mpad);
  k_red3<<<(Mpad*128)/256, 256, 0, stream>>>(P, Gatt, Skip, Mpad);
  k_al3<<<(N+255)/256, 256, 0, stream>>>(Gatt, a3s, a3d, als, ald, N);
  k_agg3<<<N, 64, 0, stream>>>(Gatt, Skip, als, ald, b3, lb3, indptr, csrc, cew,
                               (float*)d_out, N);
}

// Round 11
// 480.725 us; speedup vs baseline: 1.0774x; 1.0393x over previous
//
#include <hip/hip_runtime.h>

typedef __attribute__((ext_vector_type(8))) short s16x8;
typedef __attribute__((ext_vector_type(8))) __bf16 bf16x8;
typedef __attribute__((ext_vector_type(4))) float f32x4;

__device__ inline float bf2f(ushort u){ return __uint_as_float(((unsigned)u)<<16); }
__device__ inline ushort f2bf(float f){
  unsigned u = __float_as_uint(f);
  unsigned r = (u + 0x7fffu + ((u>>16)&1u)) >> 16;
  return (ushort)r;
}

__device__ inline void gl_lds16(const ushort* g, ushort* l){
  __builtin_amdgcn_global_load_lds(
      (const __attribute__((address_space(1))) unsigned int*)g,
      (__attribute__((address_space(3))) unsigned int*)l,
      16, 0, 0);
}

// ---------------- fused: edge-count + x->bf16 convert (independent ops) ----------------
__global__ void k_prep(const int* __restrict__ ei, int* __restrict__ counts,
                       const float* __restrict__ x, ushort* __restrict__ xb,
                       int E, int ET, int ETb, int n8valid, int n8total){
  int b = blockIdx.x;
  if (b < ETb){
    int e = b*256 + threadIdx.x;
    if (e >= ET) return;
    int dst = (e < E) ? ei[E + e] : (e - E);
    atomicAdd(&counts[dst], 1);
  } else {
    int i = (b - ETb)*256 + threadIdx.x;
    if (i >= n8total) return;
    s16x8 o = {0,0,0,0,0,0,0,0};
    if (i < n8valid){
      const float4* p = (const float4*)x + (size_t)i*2;
      float4 a = p[0], bb = p[1];
      o[0]=(short)f2bf(a.x); o[1]=(short)f2bf(a.y); o[2]=(short)f2bf(a.z); o[3]=(short)f2bf(a.w);
      o[4]=(short)f2bf(bb.x); o[5]=(short)f2bf(bb.y); o[6]=(short)f2bf(bb.z); o[7]=(short)f2bf(bb.w);
    }
    *((s16x8*)xb + i) = o;
  }
}

__global__ __launch_bounds__(1024) void k_scan(const int* __restrict__ cnt,
                                               int* __restrict__ indptr, int N){
  __shared__ int part[1024];
  int t = threadIdx.x;
  int per = (N + 1023) / 1024;
  int base = t * per;
  int s = 0;
  for (int i = 0; i < per; ++i){ int idx = base + i; if (idx < N) s += cnt[idx]; }
  part[t] = s; __syncthreads();
  for (int off = 1; off < 1024; off <<= 1){
    int v = (t >= off) ? part[t-off] : 0;
    __syncthreads();
    if (t >= off) part[t] += v;
    __syncthreads();
  }
  int run = (t == 0) ? 0 : part[t-1];
  for (int i = 0; i < per; ++i){
    int idx = base + i;
    if (idx < N){ indptr[idx] = run; run += cnt[idx]; }
  }
  if (t == 1023) indptr[N] = run;
}

__global__ void k_fill(const int* __restrict__ ei, const float* __restrict__ ew,
                       const int* __restrict__ indptr, int* __restrict__ cursor,
                       int* __restrict__ csrc, float* __restrict__ cew,
                       int E, int ET){
  int e = blockIdx.x*256 + threadIdx.x;
  if (e >= ET) return;
  int src, dst; float w;
  if (e < E){ src = ei[e]; dst = ei[E + e]; w = ew[e]; }
  else { src = dst = e - E; w = 1.0f; }
  int pos = indptr[dst] + atomicAdd(&cursor[dst], 1);
  csrc[pos] = src; cew[pos] = w;
}

// ---------------- batched weight packing: all three layers in one launch ----------------
// seg1 = 4*64 = 256 blocks (K=128,Np=2048); seg2 = 32*64 = 2048; seg3 = 32*4 = 128.
__global__ __launch_bounds__(256) void k_packB3(
    const float* __restrict__ W1, const float* __restrict__ Lw1, ushort* __restrict__ B1,
    const float* __restrict__ W2, const float* __restrict__ Lw2, ushort* __restrict__ B2,
    const float* __restrict__ W3, const float* __restrict__ Lw3, ushort* __restrict__ B3)
{
  __shared__ float tile[32][33];
  int b = blockIdx.x;
  const float *W, *L; ushort* B; int K, NW, NL, Np, nkb, lb;
  if (b < 256)      { W=W1; L=Lw1; B=B1; K=128;  NW=1024; NL=1024; Np=2048; nkb=4;  lb=b; }
  else if (b < 2304){ W=W2; L=Lw2; B=B2; K=1024; NW=1024; NL=1024; Np=2048; nkb=32; lb=b-256; }
  else              { W=W3; L=Lw3; B=B3; K=1024; NW=60;   NL=10;   Np=128;  nkb=32; lb=b-2304; }
  int k0 = (lb % nkb)*32, n0 = (lb / nkb)*32;
  int c = threadIdx.x & 31, r4 = threadIdx.x >> 5;
  #pragma unroll
  for (int rr = 0; rr < 32; rr += 8){
    int k = k0 + r4 + rr, n = n0 + c;
    float v = 0.f;
    if (k < K){
      if (n < NW)            v = W[(size_t)k*NW + n];
      else if (n < NW + NL)  v = L[(size_t)k*NL + (n - NW)];
    }
    tile[r4+rr][c] = v;
  }
  __syncthreads();
  #pragma unroll
  for (int rr = 0; rr < 32; rr += 8){
    int n = n0 + r4 + rr, k = k0 + c;
    if (n < Np && k < K) B[(size_t)n*K + k] = f2bf(tile[c][r4+rr]);
  }
}

// ---------------- split-K 128^2 GEMM (layer 3): K-slice -> f32 partials ----------------
__global__ __launch_bounds__(256) void k_gemm_sk(
    const ushort* __restrict__ A, const ushort* __restrict__ BT,
    float* __restrict__ P, int K, int kseg, int Mpad)
{
  __shared__ ushort As[128*64];
  __shared__ ushort Bs[128*64];
  const int bid = blockIdx.x;
  const int part = bid & 3;
  const size_t row0 = (size_t)(bid >> 2) * 128;
  const int kbeg = part * kseg;
  const int kend = kbeg + kseg;
  const int t = threadIdx.x;
  const int l = t & 63, w = t >> 6;
  const int wr = w >> 1, wc = w & 1;
  const int sr = l >> 3;
  const int sk = ((l & 7) ^ sr) << 3;
  const ushort* gA = A  + (row0 + w*8 + sr)*(size_t)K + sk;
  const ushort* gB = BT + (w*8 + sr)*(size_t)K + sk;
  ushort* lA = As + w*512;
  ushort* lB = Bs + w*512;
  const int rf = l & 15;
  const int g4 = l >> 4;
  f32x4 acc[4][4] = {};

  for (int k0 = kbeg; k0 < kend; k0 += 64){
    #pragma unroll
    for (int i = 0; i < 4; ++i){
      gl_lds16(gA + k0 + (size_t)(i*32)*K, lA + i*2048);
      gl_lds16(gB + k0 + (size_t)(i*32)*K, lB + i*2048);
    }
    __syncthreads();
    #pragma unroll
    for (int kk = 0; kk < 2; ++kk){
      const int koff = ((((kk<<2) | g4) ^ (rf & 7)) << 3);
      bf16x8 af[4], bfr[4];
      #pragma unroll
      for (int i = 0; i < 4; ++i)
        af[i] = __builtin_bit_cast(bf16x8, *(const s16x8*)(As + (wr*64 + i*16 + rf)*64 + koff));
      #pragma unroll
      for (int j = 0; j < 4; ++j)
        bfr[j] = __builtin_bit_cast(bf16x8, *(const s16x8*)(Bs + (wc*64 + j*16 + rf)*64 + koff));
      #pragma unroll
      for (int i = 0; i < 4; ++i)
        #pragma unroll
        for (int j = 0; j < 4; ++j)
          acc[i][j] = __builtin_amdgcn_mfma_f32_16x16x32_bf16(af[i], bfr[j], acc[i][j], 0, 0, 0);
    }
    __syncthreads();
  }

  float* Pp = P + (size_t)part * Mpad * 128;
  #pragma unroll
  for (int i = 0; i < 4; ++i){
    #pragma unroll
    for (int j = 0; j < 4; ++j){
      int gc = wc*64 + j*16 + rf;
      #pragma unroll
      for (int r = 0; r < 4; ++r){
        size_t gr = row0 + wr*64 + i*16 + (g4<<2) + r;
        Pp[gr*128 + gc] = acc[i][j][r];
      }
    }
  }
}

// reduce 4 partials -> G3 (60-col bf16) + Skip3 (10-col bf16)
__global__ void k_red3(const float* __restrict__ P, ushort* __restrict__ G3,
                       ushort* __restrict__ S3, int Mpad){
  int idx = blockIdx.x*256 + threadIdx.x;
  int row = idx >> 7, gc = idx & 127;
  if (row >= Mpad || gc >= 70) return;
  const size_t st = (size_t)Mpad*128;
  float v = P[idx] + P[idx+st] + P[idx+2*st] + P[idx+3*st];
  if (gc < 60) G3[(size_t)row*60 + gc] = f2bf(v);
  else         S3[(size_t)row*10 + (gc-60)] = f2bf(v);
}

// ---------------- 8-phase 256^2 MFMA GEMM v5 (layers 1,2): branch-free steady state ----
// Verified R10 sync skeleton: 1 barrier/phase, counted vmcnt(4), reads p1:A-lo+B-lo,
// p2:B-hi, p3:A-hi, p4:none. T = K/64 >= 2 (layer1 T=2 -> 0 steady + 2 tail iters).
#define STG8(p0, hh, ktv, offU) do { \
  const ushort* _g = (p0) + (((size_t)(hh))<<7)*(size_t)K + (((size_t)(ktv))<<6); \
  gl_lds16(_g, S + (offU) + (w<<9)); \
  gl_lds16(_g + ((size_t)K<<6), S + (offU) + 4096 + (w<<9)); \
} while(0)

#define RD_A(base_) do { _Pragma("unroll") \
  for (int i_ = 0; i_ < 4; ++i_){ \
    const int hr = wr*64 + i_*16 + rf; const int sw = hr & 7; \
    av[i_][0] = *(const bf16x8*)((base_) + hr*64 + ((g4 ^ sw) << 3)); \
    av[i_][1] = *(const bf16x8*)((base_) + hr*64 + (((4|g4) ^ sw) << 3)); } \
} while(0)

#define RD_B(base_, dst_) do { _Pragma("unroll") \
  for (int j_ = 0; j_ < 2; ++j_){ \
    const int cf = wc*32 + j_*16 + rf; const int sw = cf & 7; \
    dst_[j_][0] = *(const bf16x8*)((base_) + cf*64 + ((g4 ^ sw) << 3)); \
    dst_[j_][1] = *(const bf16x8*)((base_) + cf*64 + (((4|g4) ^ sw) << 3)); } \
} while(0)

#define MM8(mh, nh, bv_) do { \
  __builtin_amdgcn_s_setprio(1); \
  _Pragma("unroll") \
  for (int kk_ = 0; kk_ < 2; ++kk_) \
    _Pragma("unroll") \
    for (int i_ = 0; i_ < 4; ++i_) \
      _Pragma("unroll") \
      for (int j_ = 0; j_ < 2; ++j_) \
        acc[mh][nh][i_][j_] = __builtin_amdgcn_mfma_f32_16x16x32_bf16( \
            av[i_][kk_], bv_[j_][kk_], acc[mh][nh][i_][j_], 0, 0, 0); \
  __builtin_amdgcn_s_setprio(0); \
} while(0)

#define KSTEP(u_, UN1, UN2) do { \
  const int b_ = (u_) & 1; \
  const int bbase = b_ << 15; \
  const int nbase = bbase ^ 32768; \
  const ushort* Alo = S + bbase; \
  const ushort* Ahi = S + bbase + 8192; \
  const ushort* Blo = S + bbase + 16384; \
  const ushort* Bhi = S + bbase + 24576; \
  RD_A(Alo); RD_B(Blo, bvlo); \
  if (UN1) STG8(pA, 1, (u_)+1, nbase + 8192); \
  MM8(0, 0, bvlo); \
  asm volatile("s_barrier" ::: "memory"); \
  RD_B(Bhi, bvhi); \
  if (UN1) STG8(pB, 1, (u_)+1, nbase + 24576); \
  MM8(0, 1, bvhi); \
  asm volatile("s_barrier" ::: "memory"); \
  RD_A(Ahi); \
  if (UN2) STG8(pA, 0, (u_)+2, bbase); \
  MM8(1, 1, bvhi); \
  asm volatile("s_barrier" ::: "memory"); \
  if (UN2) STG8(pB, 0, (u_)+2, bbase + 16384); \
  MM8(1, 0, bvlo); \
  if (UN2) asm volatile("s_waitcnt vmcnt(4)"); \
  else     asm volatile("s_waitcnt vmcnt(0)"); \
  asm volatile("s_barrier" ::: "memory"); \
} while(0)

__global__ __launch_bounds__(512, 1) void k_gemm8(
    const ushort* __restrict__ A, const ushort* __restrict__ BT,
    ushort* __restrict__ Gatt, ushort* __restrict__ Skip,
    int K, int GW, int CPX)
{
  __shared__ ushort S[65536];                  // 128 KiB: 2 bufs x (A 32KB + B 32KB)
  const int bid = blockIdx.x;
  const int lb = (bid & 7)*CPX + (bid >> 3);   // XCD-chunked bijection (grid % 8 == 0)
  const size_t row0 = (size_t)(lb >> 3) * 256; // NCB = 8 col tiles
  const size_t col0 = (size_t)(lb & 7) * 256;
  const int t = threadIdx.x;
  const int l = t & 63, w = t >> 6;            // 8 waves
  const int wr = w >> 2, wc = w & 3;           // 2 x 4 wave grid
  const int rf = l & 15, g4 = l >> 4;
  const int T = K >> 6;                        // >= 2

  const int r0 = t >> 3, s0 = t & 7;
  const ushort* pA = A  + (row0 + r0)*(size_t)K + ((s0 ^ (r0 & 7)) << 3);
  const ushort* pB = BT + (col0 + r0)*(size_t)K + ((s0 ^ (r0 & 7)) << 3);

  f32x4 acc[2][2][4][2] = {};
  bf16x8 av[4][2], bvlo[2][2], bvhi[2][2];

  // prologue: 4 halves of kt0 + A-lo/B-lo of kt1 (12 loads)
  STG8(pA, 0, 0, 0);
  STG8(pB, 0, 0, 16384);
  STG8(pA, 1, 0, 8192);
  STG8(pB, 1, 0, 24576);
  STG8(pA, 0, 1, 32768);
  STG8(pB, 0, 1, 49152);
  asm volatile("s_waitcnt vmcnt(4)");          // kt0's 4 halves complete; 4 loads in flight
  asm volatile("s_barrier" ::: "memory");

  int u = 0;
  for (; u + 2 < T; ++u) KSTEP(u, true, true); // steady state, branch-free stages
  KSTEP(u, true, false); ++u;                  // u = T-2
  KSTEP(u, false, false);                      // u = T-1

  ushort* outp; int cb;
  if ((int)col0 < GW){ outp = Gatt; cb = (int)col0; }
  else               { outp = Skip; cb = (int)col0 - GW; }
  #pragma unroll
  for (int mh = 0; mh < 2; ++mh)
    #pragma unroll
    for (int i = 0; i < 4; ++i)
      #pragma unroll
      for (int rr = 0; rr < 4; ++rr){
        size_t gr = row0 + mh*128 + wr*64 + i*16 + (g4<<2) + rr;
        ushort* rp = outp + gr*1024 + cb;
        #pragma unroll
        for (int nh = 0; nh < 2; ++nh)
          #pragma unroll
          for (int j = 0; j < 2; ++j)
            rp[nh*128 + wc*32 + j*16 + rf] = f2bf(acc[mh][nh][i][j][rr]);
      }
}

// ---------------- attention logits (layers 1-2: H=4, C=256) ----------------
__global__ __launch_bounds__(256) void k_al(const ushort* __restrict__ Gatt,
    const float* __restrict__ a_s, const float* __restrict__ a_d,
    float* __restrict__ als, float* __restrict__ ald, int N){
  int gw = (blockIdx.x*blockDim.x + threadIdx.x) >> 6;
  int l = threadIdx.x & 63;
  if (gw >= N) return;
  const ushort* row = Gatt + (size_t)gw*1024;
  int c0 = l*16;
  s16x8 v0 = *(const s16x8*)(row + c0);
  s16x8 v1 = *(const s16x8*)(row + c0 + 8);
  float ps = 0.f, pd = 0.f;
  #pragma unroll
  for (int q = 0; q < 8; ++q){
    float f0 = bf2f((ushort)v0[q]), f1 = bf2f((ushort)v1[q]);
    ps += f0*a_s[c0+q] + f1*a_s[c0+8+q];
    pd += f0*a_d[c0+q] + f1*a_d[c0+8+q];
  }
  #pragma unroll
  for (int off = 8; off; off >>= 1){
    ps += __shfl_down(ps, off);
    pd += __shfl_down(pd, off);
  }
  if ((l & 15) == 0){
    als[(size_t)gw*4 + (l>>4)] = ps;
    ald[(size_t)gw*4 + (l>>4)] = pd;
  }
}

// ---------------- softmax + aggregate + bias + skip + ELU: wave-per-node ----------------
__global__ __launch_bounds__(256) void k_agg(
    const ushort* __restrict__ Gatt,
    const ushort* __restrict__ Skip,
    const float*  __restrict__ als,
    const float*  __restrict__ ald,
    const float*  __restrict__ bias,
    const float*  __restrict__ lbias,
    const int*    __restrict__ indptr,
    const int*    __restrict__ csrc,
    const float*  __restrict__ cew,
    ushort* __restrict__ Hout,
    int N)
{
  const int t = threadIdx.x;
  const int l = t & 63, w = t >> 6;
  const int n = blockIdx.x*4 + w;
  const int h2 = l >> 4;
  const int col = l*16;
  if (n >= N){
    s16x8 z = {0,0,0,0,0,0,0,0};
    *(s16x8*)(Hout + (size_t)n*1024 + col)     = z;
    *(s16x8*)(Hout + (size_t)n*1024 + col + 8) = z;
    return;
  }
  const int beg = indptr[n];
  const int deg = indptr[n+1] - beg;
  const int hh = l & 3;
  const float aldh = ald[(size_t)n*4 + hh];

  // pass 1: online per-head max / denominator (lane tracks head hh)
  float m = -1e30f, d = 0.f;
  for (int c0 = 0; c0 < deg; c0 += 16){
    int i = c0 + (l >> 2);
    bool act = (i < deg);
    float e = -1e30f;
    if (act){
      int s = csrc[beg + i];
      float r_ = als[(size_t)s*4 + hh] + aldh;
      e = r_ > 0.f ? r_ : 0.2f*r_;
    }
    float cm = e;
    #pragma unroll
    for (int o = 4; o < 64; o <<= 1) cm = fmaxf(cm, __shfl_xor(cm, o));
    float nm = fmaxf(m, cm);
    float ex = act ? __expf(e - nm) : 0.f;
    #pragma unroll
    for (int o = 4; o < 64; o <<= 1) ex += __shfl_xor(ex, o);
    d = d * __expf(m - nm) + ex;
    m = nm;
  }
  d += 1e-16f;
  const float inv_d = 1.0f / d;

  // pass 2: weights + gather (2 edges in flight)
  float a[16];
  #pragma unroll
  for (int q = 0; q < 16; ++q) a[q] = 0.f;
  const ushort* gbase = Gatt + col;
  for (int c0 = 0; c0 < deg; c0 += 16){
    int i = c0 + (l >> 2);
    int nc = min(16, deg - c0);
    float wv = 0.f; int sv = 0;
    if (i < deg){
      sv = csrc[beg + i];
      float r_ = als[(size_t)sv*4 + hh] + aldh;
      float e = r_ > 0.f ? r_ : 0.2f*r_;
      wv = __expf(e - m) * inv_d * cew[beg + i];
    }
    int jj = 0;
    for (; jj + 1 < nc; jj += 2){
      float wg0 = __shfl(wv, (jj << 2) | h2);
      int   sg0 = __shfl(sv, jj << 2);
      float wg1 = __shfl(wv, ((jj+1) << 2) | h2);
      int   sg1 = __shfl(sv, (jj+1) << 2);
      const ushort* rp0 = gbase + (size_t)sg0*1024;
      const ushort* rp1 = gbase + (size_t)sg1*1024;
      s16x8 x0 = *(const s16x8*)rp0;
      s16x8 x1 = *(const s16x8*)(rp0 + 8);
      s16x8 y0 = *(const s16x8*)rp1;
      s16x8 y1 = *(const s16x8*)(rp1 + 8);
      #pragma unroll
      for (int q = 0; q < 8; ++q){
        a[q]   += wg0 * bf2f((ushort)x0[q]) + wg1 * bf2f((ushort)y0[q]);
        a[q+8] += wg0 * bf2f((ushort)x1[q]) + wg1 * bf2f((ushort)y1[q]);
      }
    }
    if (jj < nc){
      float wg = __shfl(wv, (jj << 2) | h2);
      int   s  = __shfl(sv, jj << 2);
      const ushort* rp = gbase + (size_t)s*1024;
      s16x8 h0 = *(const s16x8*)rp;
      s16x8 h1 = *(const s16x8*)(rp + 8);
      #pragma unroll
      for (int q = 0; q < 8; ++q){
        a[q]   += wg * bf2f((ushort)h0[q]);
        a[q+8] += wg * bf2f((ushort)h1[q]);
      }
    }
  }

  s16x8 sk0 = *(const s16x8*)(Skip + (size_t)n*1024 + col);
  s16x8 sk1 = *(const s16x8*)(Skip + (size_t)n*1024 + col + 8);
  s16x8 ov0, ov1;
  #pragma unroll
  for (int q = 0; q < 8; ++q){
    float v = a[q] + bias[col+q] + lbias[col+q] + bf2f((ushort)sk0[q]);
    v = v > 0.f ? v : __expf(v) - 1.f;
    ov0[q] = (short)f2bf(v);
    float v2 = a[q+8] + bias[col+8+q] + lbias[col+8+q] + bf2f((ushort)sk1[q]);
    v2 = v2 > 0.f ? v2 : __expf(v2) - 1.f;
    ov1[q] = (short)f2bf(v2);
  }
  *(s16x8*)(Hout + (size_t)n*1024 + col)     = ov0;
  *(s16x8*)(Hout + (size_t)n*1024 + col + 8) = ov1;
}

// ---------------- layer 3: logits (H=6, C=10) ----------------
__global__ void k_al3(const ushort* __restrict__ G3, const float* __restrict__ a_s,
                      const float* __restrict__ a_d,
                      float* __restrict__ als, float* __restrict__ ald, int N){
  int n = blockIdx.x*256 + threadIdx.x;
  if (n >= N) return;
  const ushort* row = G3 + (size_t)n*60;
  #pragma unroll
  for (int h = 0; h < 6; ++h){
    float ps = 0.f, pd = 0.f;
    #pragma unroll
    for (int c = 0; c < 10; ++c){
      float v = bf2f(row[h*10 + c]);
      ps += v * a_s[h*10 + c];
      pd += v * a_d[h*10 + c];
    }
    als[(size_t)n*6 + h] = ps;
    ald[(size_t)n*6 + h] = pd;
  }
}

// ---------------- layer 3: edge-parallel online softmax + aggregate + mean ----------------
__global__ __launch_bounds__(64) void k_agg3(
    const ushort* __restrict__ G3,
    const ushort* __restrict__ Skip3,
    const float*  __restrict__ als,
    const float*  __restrict__ ald,
    const float*  __restrict__ b3,
    const float*  __restrict__ lb3,
    const int*    __restrict__ indptr,
    const int*    __restrict__ csrc,
    const float*  __restrict__ cew,
    float* __restrict__ out, int N)
{
  const int n = blockIdx.x;
  const int l = threadIdx.x;
  const int beg = indptr[n], deg = indptr[n+1] - beg;
  __shared__ float s_aldh[6];
  __shared__ int   s_src[64];
  __shared__ float s_wgt[64][6];
  __shared__ float s_o[6][10];
  if (l < 6) s_aldh[l] = ald[(size_t)n*6 + l];
  __syncthreads();
  float m0=-1e30f,m1=-1e30f,m2=-1e30f,m3=-1e30f,m4=-1e30f,m5=-1e30f;
  float d0=0.f,d1=0.f,d2=0.f,d3=0.f,d4=0.f,d5=0.f;
  for (int c0 = 0; c0 < deg; c0 += 64){
    int nc = min(64, deg - c0);
    bool act = l < nc;
    int s = act ? csrc[beg + c0 + l] : 0;
#define HP(hh, mm, dd) { \
    float e = -1e30f; \
    if (act){ float r_ = als[(size_t)s*6 + hh] + s_aldh[hh]; e = r_ > 0.f ? r_ : 0.2f*r_; } \
    float cm = e; \
    for (int o_ = 32; o_; o_ >>= 1) cm = fmaxf(cm, __shfl_xor(cm, o_)); \
    float nm = fmaxf(mm, cm); \
    float ex = act ? __expf(e - nm) : 0.f; \
    for (int o_ = 32; o_; o_ >>= 1) ex += __shfl_xor(ex, o_); \
    dd = dd * __expf(mm - nm) + ex; mm = nm; }
    HP(0,m0,d0) HP(1,m1,d1) HP(2,m2,d2) HP(3,m3,d3) HP(4,m4,d4) HP(5,m5,d5)
#undef HP
  }
  const int h = l / 10, c = l % 10;
  float o = 0.f;
  for (int c0 = 0; c0 < deg; c0 += 64){
    int nc = min(64, deg - c0);
    if (l < nc){
      int s = csrc[beg + c0 + l];
      s_src[l] = s;
      float w_ = cew[beg + c0 + l];
#define WP(hh, mm, dd) { \
      float r_ = als[(size_t)s*6 + hh] + s_aldh[hh]; \
      float e = r_ > 0.f ? r_ : 0.2f*r_; \
      s_wgt[l][hh] = __expf(e - mm) / (dd + 1e-16f) * w_; }
      WP(0,m0,d0) WP(1,m1,d1) WP(2,m2,d2) WP(3,m3,d3) WP(4,m4,d4) WP(5,m5,d5)
#undef WP
    }
    __syncthreads();
    if (l < 60){
      for (int i = 0; i < nc; ++i)
        o += s_wgt[i][h] * bf2f(G3[(size_t)s_src[i]*60 + l]);
    }
    __syncthreads();
  }
  if (l < 60) s_o[h][c] = o;
  __syncthreads();
  if (l < 10){
    float v = (s_o[0][l]+s_o[1][l]+s_o[2][l]+s_o[3][l]+s_o[4][l]+s_o[5][l]) * (1.0f/6.0f);
    v += b3[l] + lb3[l] + bf2f(Skip3[(size_t)n*10 + l]);
    out[(size_t)n*10 + l] = v;
  }
}

// ---------------- host ----------------
extern "C" void kernel_launch(void* const* d_in, const int* in_sizes, int n_in,
                              void* d_out, int out_size, void* d_ws, size_t ws_size,
                              hipStream_t stream)
{
  const int N = 20000, F = 128, E = 320000, ET = E + N;
  const int Mpad = 20224;            // 79*256
  const int F1 = 1024, NT = 2048;
  const int NWG2 = (Mpad/256)*(NT/256);   // 632, %8==0

  const float* x   = (const float*)d_in[0];
  const int*   ei  = (const int*)  d_in[1];
  const float* ew  = (const float*)d_in[2];
  const float* W1  = (const float*)d_in[3];
  const float* a1s = (const float*)d_in[4];
  const float* a1d = (const float*)d_in[5];
  const float* b1  = (const float*)d_in[6];
  const float* lw1 = (const float*)d_in[7];
  const float* lb1 = (const float*)d_in[8];
  const float* W2  = (const float*)d_in[9];
  const float* a2s = (const float*)d_in[10];
  const float* a2d = (const float*)d_in[11];
  const float* b2  = (const float*)d_in[12];
  const float* lw2 = (const float*)d_in[13];
  const float* lb2 = (const float*)d_in[14];
  const float* W3  = (const float*)d_in[15];
  const float* a3s = (const float*)d_in[16];
  const float* a3d = (const float*)d_in[17];
  const float* b3  = (const float*)d_in[18];
  const float* lw3 = (const float*)d_in[19];
  const float* lb3 = (const float*)d_in[20];

  char* ws = (char*)d_ws;
  size_t off = 0;
  auto alloc = [&](size_t bytes) -> void* {
    void* p = ws + off;
    off = (off + bytes + 255) & ~(size_t)255;
    return p;
  };
  ushort* Gatt = (ushort*)alloc((size_t)Mpad*F1*2);
  ushort* Skip = (ushort*)alloc((size_t)Mpad*F1*2);
  ushort* H    = (ushort*)alloc((size_t)Mpad*F1*2);
  ushort* xb   = (ushort*)alloc((size_t)Mpad*F*2);
  ushort* BT1  = (ushort*)alloc((size_t)NT*F*2);     // [2048][128]
  ushort* BT2  = (ushort*)alloc((size_t)NT*F1*2);    // [2048][1024]
  ushort* BT3  = (ushort*)alloc((size_t)128*F1*2);   // [128][1024]
  float*  P    = (float*) alloc((size_t)4*Mpad*128*4);
  float*  als  = (float*) alloc((size_t)N*6*4);
  float*  ald  = (float*) alloc((size_t)N*6*4);
  int*    counts = (int*)alloc((size_t)2*N*4);
  int*    cursor = counts + N;
  int*    indptr = (int*)alloc((size_t)(N+1)*4);
  int*    csrc   = (int*)alloc((size_t)ET*4);
  float*  cew    = (float*)alloc((size_t)ET*4);
  if (off > ws_size) return;

  const int ETb = (ET + 255)/256;
  const int n8tot = Mpad*F/8;
  const int n8b = (n8tot + 255)/256;

  hipMemsetAsync(counts, 0, (size_t)2*N*4, stream);
  k_prep<<<ETb + n8b, 256, 0, stream>>>(ei, counts, x, xb, E, ET, ETb, N*F/8, n8tot);
  k_scan<<<1, 1024, 0, stream>>>(counts, indptr, N);
  k_fill<<<(ET+255)/256, 256, 0, stream>>>(ei, ew, indptr, cursor, csrc, cew, E, ET);
  k_packB3<<<2432, 256, 0, stream>>>(W1, lw1, BT1, W2, lw2, BT2, W3, lw3, BT3);

  // ---- layer 1 (8-phase 256^2, K=128 -> T=2) ----
  k_gemm8<<<dim3(NWG2), 512, 0, stream>>>(xb, BT1, Gatt, Skip, F, 1024, NWG2/8);
  k_al<<<(N+3)/4, 256, 0, stream>>>(Gatt, a1s, a1d, als, ald, N);
  k_agg<<<Mpad/4, 256, 0, stream>>>(Gatt, Skip, als, ald, b1, lb1, indptr, csrc, cew, H, N);

  // ---- layer 2 (8-phase 256^2, K=1024 -> T=16) ----
  k_gemm8<<<dim3(NWG2), 512, 0, stream>>>(H, BT2, Gatt, Skip, F1, 1024, NWG2/8);
  k_al<<<(N+3)/4, 256, 0, stream>>>(Gatt, a2s, a2d, als, ald, N);
  k_agg<<<Mpad/4, 256, 0, stream>>>(Gatt, Skip, als, ald, b2, lb2, indptr, csrc, cew, H, N);

  // ---- layer 3 (split-K path) ----
  k_gemm_sk<<<dim3((Mpad/128)*4), 256, 0, stream>>>(H, BT3, P, F1, F1/4, Mpad);
  k_red3<<<(Mpad*128)/256, 256, 0, stream>>>(P, Gatt, Skip, Mpad);
  k_al3<<<(N+255)/256, 256, 0, stream>>>(Gatt, a3s, a3d, als, ald, N);
  k_agg3<<<N, 64, 0, stream>>>(Gatt, Skip, als, ald, b3, lb3, indptr, csrc, cew,
                               (float*)d_out, N);
}